// Round 5
// baseline (611.847 us; speedup 1.0000x reference)
//
#include <hip/hip_runtime.h>
#include <math.h>

#define KK 8
#define H 250          // SIZE == h1
#define MDIM 576
#define NB 2048
#define HA 100
#define ROWS (NB*KK)   // 16384
#define PROWS (ROWS*7) // 114688 pair rows
#define PQS 512        // PQ row stride: P at 0..249, Q at 256..505 (16B-aligned)
#define KP 1088        // padded K for out GEMM (1076 -> 34*32)
#define EPS 1e-5f

#define RCA 112        // pair rows per k_ca block (16 groups * 7)
#define GCA 16
#define NCA 384        // 250 ctx + 100 att + pad
#define SSTR 384       // epilogue slab stride (slab aliases Bs: 16*384*4 = 24576 B)

typedef unsigned short ushort_t;
typedef short short8 __attribute__((ext_vector_type(8)));
typedef float f32x4 __attribute__((ext_vector_type(4)));

__device__ __forceinline__ void wave_reduce2(float& a, float& b) {
#pragma unroll
    for (int m = 1; m < 64; m <<= 1) {
        a += __shfl_xor(a, m, 64);
        b += __shfl_xor(b, m, 64);
    }
}
__device__ __forceinline__ float wave_reduce1(float a) {
#pragma unroll
    for (int m = 1; m < 64; m <<= 1) a += __shfl_xor(a, m, 64);
    return a;
}

__device__ __forceinline__ void async_copy16(const void* g, void* l) {
    __builtin_amdgcn_global_load_lds(
        (const __attribute__((address_space(1))) void*)g,
        (__attribute__((address_space(3))) void*)l, 16, 0, 0);
}

__device__ __forceinline__ ushort_t f2bf(float v) {
    union { float f; unsigned int u; } c; c.f = v;
    unsigned int x = c.u;
    x += 0x7fff + ((x >> 16) & 1);   // RNE
    return (ushort_t)(x >> 16);
}

// s1 = LN(relu(state @ enc_W + enc_b)) -> Abuf cols [0,250) bf16
__global__ __launch_bounds__(256) void k_enc(const float* __restrict__ state,
    const float* __restrict__ W, const float* __restrict__ bias,
    const float* __restrict__ gam, const float* __restrict__ bet,
    ushort_t* __restrict__ Abuf)
{
    __shared__ __align__(16) float st[4][H][8];   // [wave][k][row]
    const int wave = threadIdx.x >> 6, lane = threadIdx.x & 63;
    const int row0 = (blockIdx.x * 4 + wave) * 8;

#pragma unroll
    for (int r = 0; r < 8; ++r)
        for (int kk = lane; kk < H; kk += 64)
            st[wave][kk][r] = state[(size_t)(row0 + r) * H + kk];
    __syncthreads();

    int c[4]; bool val[4]; const float* pW[4];
#pragma unroll
    for (int u = 0; u < 4; ++u) {
        c[u] = lane + 64 * u; val[u] = c[u] < H;
        pW[u] = W + (val[u] ? c[u] : 0);
    }
    float acc[8][4] = {};
    for (int kk = 0; kk < H; ++kk) {
        const float4 sA = *(const float4*)&st[wave][kk][0];
        const float4 sB = *(const float4*)&st[wave][kk][4];
        const float s[8] = {sA.x,sA.y,sA.z,sA.w,sB.x,sB.y,sB.z,sB.w};
        float w[4];
#pragma unroll
        for (int u = 0; u < 4; ++u) { w[u] = *pW[u]; pW[u] += H; }
#pragma unroll
        for (int u = 0; u < 4; ++u)
#pragma unroll
            for (int r = 0; r < 8; ++r)
                acc[r][u] = fmaf(s[r], w[u], acc[r][u]);
    }

    float bv[4], gv[4], btv[4];
#pragma unroll
    for (int u = 0; u < 4; ++u) {
        bv[u]  = val[u] ? bias[c[u]] : 0.f;
        gv[u]  = val[u] ? gam[c[u]]  : 0.f;
        btv[u] = val[u] ? bet[c[u]]  : 0.f;
    }
#pragma unroll
    for (int r = 0; r < 8; ++r) {
        float y[4]; float sm = 0.f, sq = 0.f;
#pragma unroll
        for (int u = 0; u < 4; ++u) {
            float z = val[u] ? fmaxf(acc[r][u] + bv[u], 0.f) : 0.f;
            y[u] = z; sm += z; sq += z * z;
        }
        wave_reduce2(sm, sq);
        const float mu = sm * (1.f / H);
        const float rs = rsqrtf(sq * (1.f / H) - mu * mu + EPS);
#pragma unroll
        for (int u = 0; u < 4; ++u) if (val[u]) {
            const float o = (y[u] - mu) * rs * gv[u] + btv[u];
            Abuf[(size_t)(row0 + r) * KP + c[u]] = f2bf(o);
        }
    }
}

// generic bf16 MFMA GEMM: C[m][n] = sum_k A[m][k]*B[n][k] (+bias[n])
__global__ __launch_bounds__(256) void k_gemm(
    const ushort_t* __restrict__ A, int lda,
    const ushort_t* __restrict__ B, int ldb,
    float* __restrict__ C, int ldc,
    const float* __restrict__ bias,
    int ksteps, int ntiles, int nlim)
{
    __shared__ __align__(16) ushort_t As[64 * 32];
    __shared__ __align__(16) ushort_t Bs[64 * 32];
    const int tid  = threadIdx.x;
    const int lane = tid & 63, wave = tid >> 6;
    const int wm = wave >> 1, wn = wave & 1;
    const int m0 = ((int)blockIdx.x / ntiles) * 64;
    const int n0 = ((int)blockIdx.x % ntiles) * 64;

    const int srow = tid >> 2;
    const int cs   = tid & 3;
    const int cl   = cs ^ ((srow >> 1) & 3);
    const ushort_t* gA = A + (size_t)(m0 + srow) * lda + cl * 8;
    const ushort_t* gB = B + (size_t)(n0 + srow) * ldb + cl * 8;
    ushort_t* lA = &As[tid * 8];
    ushort_t* lB = &Bs[tid * 8];

    const int q  = lane >> 4;
    const int fr = lane & 15;
    int aoff[2], boff[2];
#pragma unroll
    for (int s = 0; s < 2; ++s) {
        const int ra = wm * 32 + s * 16 + fr;
        aoff[s] = (ra * 4 + (q ^ ((ra >> 1) & 3))) * 8;
        const int rb = wn * 32 + s * 16 + fr;
        boff[s] = (rb * 4 + (q ^ ((rb >> 1) & 3))) * 8;
    }

    f32x4 acc[2][2] = {};
    for (int ks = 0; ks < ksteps; ++ks) {
        const int k0 = ks * 32;
        async_copy16(gA + k0, lA);
        async_copy16(gB + k0, lB);
        __syncthreads();
        short8 a[2], b[2];
#pragma unroll
        for (int s = 0; s < 2; ++s) {
            a[s] = *(const short8*)&As[aoff[s]];
            b[s] = *(const short8*)&Bs[boff[s]];
        }
#pragma unroll
        for (int ms = 0; ms < 2; ++ms)
#pragma unroll
            for (int ns = 0; ns < 2; ++ns)
                acc[ms][ns] = __builtin_amdgcn_mfma_f32_16x16x32_bf16(
                    a[ms], b[ns], acc[ms][ns], 0, 0, 0);
        __syncthreads();
    }

#pragma unroll
    for (int ms = 0; ms < 2; ++ms)
#pragma unroll
        for (int ns = 0; ns < 2; ++ns) {
            const int n_abs = n0 + wn * 32 + ns * 16 + fr;
            if (n_abs >= nlim) continue;
            const float bv = bias ? bias[n_abs] : 0.f;
#pragma unroll
            for (int reg = 0; reg < 4; ++reg) {
                const int m_abs = m0 + wm * 32 + ms * 16 + q * 4 + reg;
                C[(size_t)m_abs * ldc + n_abs] = acc[ms][ns][reg] + bv;
            }
        }
}

// Per-pair-row LN stats of relu(P+Q+core_b): massively parallel, hides shfl chains.
// One wave per pair row; Gstats[r] = {mu, rs}.
__global__ __launch_bounds__(256) void k_stats(const float* __restrict__ PQ,
    const float* __restrict__ core_b, float* __restrict__ Gstats)
{
    const int wave = threadIdx.x >> 6, lane = threadIdx.x & 63;
    const int r = blockIdx.x * 4 + wave;        // pair row 0..114687
    const int g = r / 7, jj = r - g * 7;
    const int i = g & 7;
    const int j = jj + (jj >= i ? 1 : 0);
    const int qr = (g & ~7) + j;
    const int c = lane * 4;

    const float4 pv = *(const float4*)&PQ[(size_t)g  * PQS + c];
    const float4 qv = *(const float4*)&PQ[(size_t)qr * PQS + 256 + c];
    const float pe[4] = {pv.x, pv.y, pv.z, pv.w};
    const float qe[4] = {qv.x, qv.y, qv.z, qv.w};
    float sm = 0.f, sq = 0.f;
#pragma unroll
    for (int t = 0; t < 4; ++t) {
        const float z = (c + t < H) ? fmaxf(pe[t] + qe[t] + core_b[c + t], 0.f) : 0.f;
        sm += z; sq += z * z;
    }
    wave_reduce2(sm, sq);
    if (lane == 0) {
        const float mu = sm * (1.f / H);
        Gstats[r * 2]     = mu;
        Gstats[r * 2 + 1] = rsqrtf(sq * (1.f / H) - mu * mu + EPS);
    }
}

// fused core-LN -> [ctxW|attW1] MFMA GEMM -> LNs -> sigmoid -> partner-sum
// One block per 16 groups (112 pair rows). 512 threads = 8 waves (2x4 tile grid).
// LDS 48.1 KB -> 3 blocks/CU. Epilogue slab aliases Bs (dead after GEMM loop).
__global__ __launch_bounds__(512) void k_ca(
    const float* __restrict__ PQ, const float* __restrict__ Gstats,
    const float* __restrict__ core_b, const float* __restrict__ core_g, const float* __restrict__ core_bt,
    const ushort_t* __restrict__ Wca,   // [384][256] bf16
    const float* __restrict__ ctx_b, const float* __restrict__ ctx_g, const float* __restrict__ ctx_bt,
    const float* __restrict__ att_b1, const float* __restrict__ att_g, const float* __restrict__ att_bt,
    const float* __restrict__ attW2, const float* __restrict__ att_b2,
    ushort_t* __restrict__ Abuf)
{
    __shared__ __align__(16) ushort_t As[RCA * 32];   // 7168 B
    __shared__ __align__(16) ushort_t Bs[NCA * 32];   // 24576 B (aliased as Sred after loop)
    __shared__ float effs[GCA * 256];                 // 16384 B
    float* Sred = (float*)Bs;                         // 16 x 384 f32 = 24576 B

    const int tid = threadIdx.x, lane = tid & 63, wave = tid >> 6;
    const int g0 = (int)blockIdx.x * GCA;

    for (int idx = tid; idx < GCA * 256; idx += 512) effs[idx] = 0.f;

    const int wm = wave >> 2, wn = wave & 3;          // 2 x 4 wave grid
    const int q = lane >> 4, fr = lane & 15;
    const int nmt = wm ? 3 : 4;                        // wm0: mt 0..3, wm1: mt 4..6

    // A-staging mapping: thread -> (row, chunk); stats preloaded from k_stats
    const int ar  = tid >> 2;
    const int acb = tid & 3;
    const bool s_on = (ar < RCA);
    int s_g = 0, s_qr = 0; float s_mu = 0.f, s_rs = 0.f;
    if (s_on) {
        const int gl = ar / 7, jj = ar - gl * 7;
        s_g = g0 + gl;
        const int i = s_g & 7;
        const int j = jj + (jj >= i ? 1 : 0);
        s_qr = (s_g & ~7) + j;
        const int rglob = (int)blockIdx.x * RCA + ar;
        s_mu = Gstats[rglob * 2]; s_rs = Gstats[rglob * 2 + 1];
    }

    f32x4 acc[4][6] = {};
    for (int ks = 0; ks < 8; ++ks) {
        const int k0 = ks * 32;
        // A: recompute core_out bf16 slice (stats known -> purely local)
        if (s_on) {
            const int kc = k0 + acb * 8;
            const float4 p0 = *(const float4*)&PQ[(size_t)s_g  * PQS + kc];
            const float4 p1 = *(const float4*)&PQ[(size_t)s_g  * PQS + kc + 4];
            const float4 q0 = *(const float4*)&PQ[(size_t)s_qr * PQS + 256 + kc];
            const float4 q1 = *(const float4*)&PQ[(size_t)s_qr * PQS + 256 + kc + 4];
            const float pe[8] = {p0.x,p0.y,p0.z,p0.w,p1.x,p1.y,p1.z,p1.w};
            const float qe[8] = {q0.x,q0.y,q0.z,q0.w,q1.x,q1.y,q1.z,q1.w};
            short8 ob;
#pragma unroll
            for (int e = 0; e < 8; ++e) {
                const int kk = kc + e;
                float v = 0.f;
                if (kk < H) {
                    const float z = fmaxf(pe[e] + qe[e] + core_b[kk], 0.f);
                    v = (z - s_mu) * s_rs * core_g[kk] + core_bt[kk];
                }
                ob[e] = (short)f2bf(v);
            }
            const int pos = acb ^ ((ar >> 1) & 3);
            *(short8*)&As[(ar * 4 + pos) * 8] = ob;
        }
        // B: async global->LDS (1536 16B chunks over 512 threads)
#pragma unroll
        for (int it = 0; it < 3; ++it) {
            const int ci  = it * 512 + tid;
            const int rb  = ci >> 2, cb2 = ci & 3;
            const int clb = cb2 ^ ((rb >> 1) & 3);
            async_copy16(Wca + (size_t)rb * 256 + k0 + clb * 8, &Bs[ci * 8]);
        }
        __syncthreads();
        short8 a[4];
#pragma unroll
        for (int mtl = 0; mtl < 4; ++mtl) {
            if (mtl < nmt) {
                const int row = wm * 64 + mtl * 16 + fr;
                a[mtl] = *(const short8*)&As[(row * 4 + (q ^ ((row >> 1) & 3))) * 8];
            }
        }
#pragma unroll
        for (int ntl = 0; ntl < 6; ++ntl) {
            const int n = wn * 96 + ntl * 16 + fr;
            const short8 b = *(const short8*)&Bs[(n * 4 + (q ^ ((n >> 1) & 3))) * 8];
#pragma unroll
            for (int mtl = 0; mtl < 4; ++mtl)
                if (mtl < nmt)
                    acc[mtl][ntl] = __builtin_amdgcn_mfma_f32_16x16x32_bf16(
                        a[mtl], b, acc[mtl][ntl], 0, 0, 0);
        }
        __syncthreads();
    }

    // ---- epilogue: preload row-invariant per-lane constants ----
    const float ab2 = att_b2[0];
    float xb[6], xg[6], xbt[6], w2[6]; bool isC[6], isA[6];
#pragma unroll
    for (int u = 0; u < 6; ++u) {
        const int cc = lane + 64 * u;
        isC[u] = cc < H;
        isA[u] = (cc >= H) && (cc < H + HA);
        if (isC[u])      { xb[u] = ctx_b[cc]; xg[u] = ctx_g[cc]; xbt[u] = ctx_bt[cc]; w2[u] = 0.f; }
        else if (isA[u]) { const int ca = cc - H;
                           xb[u] = att_b1[ca]; xg[u] = att_g[ca]; xbt[u] = att_bt[ca]; w2[u] = attW2[ca]; }
        else             { xb[u] = xg[u] = xbt[u] = w2[u] = 0.f; }
    }

#pragma unroll
    for (int mt = 0; mt < 7; ++mt) {
        const int mwm = (mt >= 4) ? 1 : 0;   // compile-time
        const int mtl = mt - 4 * mwm;        // compile-time
        __syncthreads();
        if (wm == mwm) {
#pragma unroll
            for (int ntl = 0; ntl < 6; ++ntl) {
                const int col = wn * 96 + ntl * 16 + fr;
#pragma unroll
                for (int reg = 0; reg < 4; ++reg)
                    Sred[(q * 4 + reg) * SSTR + col] = acc[mtl][ntl][reg];
            }
        }
        __syncthreads();
#pragma unroll
        for (int rh = 0; rh < 2; ++rh) {
            const int rloc = wave + rh * 8;          // 0..15
            const int r    = mt * 16 + rloc;         // 0..111
            const int gl   = r / 7;
            float sv[6];
            float smc = 0.f, sqc = 0.f, sma = 0.f, sqa = 0.f;
#pragma unroll
            for (int u = 0; u < 6; ++u) {
                const int cc = lane + 64 * u;
                const float v = Sred[rloc * SSTR + cc];
                if (isC[u]) {
                    const float z = fmaxf(v + xb[u], 0.f);
                    sv[u] = z; smc += z; sqc += z * z;
                } else if (isA[u]) {
                    const float za = tanhf(v + xb[u]);
                    sv[u] = za; sma += za; sqa += za * za;
                } else sv[u] = 0.f;
            }
            wave_reduce2(smc, sqc);
            wave_reduce2(sma, sqa);
            const float muC = smc * (1.f / H);
            const float rsC = rsqrtf(sqc * (1.f / H) - muC * muC + EPS);
            const float muA = sma * (1.f / HA);
            const float rsA = rsqrtf(sqa * (1.f / HA) - muA * muA + EPS);
            float dot = 0.f;
#pragma unroll
            for (int u = 0; u < 6; ++u) {
                if (isA[u]) {
                    const float ath = (sv[u] - muA) * rsA * xg[u] + xbt[u];
                    dot += ath * w2[u];
                }
            }
            dot = wave_reduce1(dot);
            const float ag = 1.f / (1.f + expf(-(dot + ab2)));
#pragma unroll
            for (int u = 0; u < 4; ++u) {
                const int cc = lane + 64 * u;
                if (isC[u]) {
                    const float ctxo = (sv[u] - muC) * rsC * xg[u] + xbt[u];
                    atomicAdd(&effs[gl * 256 + cc], ag * ctxo);
                }
            }
        }
    }
    __syncthreads();
    for (int idx = tid; idx < GCA * 256; idx += 512) {
        const int gl = idx >> 8, cc = idx & 255;
        if (cc < H)
            Abuf[(size_t)(g0 + gl) * KP + H + cc] = f2bf(effs[idx]);
    }
}

// Abuf cols [500,1088): x (bf16) + zero pad
__global__ __launch_bounds__(256) void k_prepx(const float* __restrict__ x,
                                               ushort_t* __restrict__ Abuf)
{
    const int row = blockIdx.x;
    for (int c = 500 + threadIdx.x; c < KP; c += 256) {
        const float v = (c < 500 + MDIM) ? x[(size_t)row * MDIM + (c - 500)] : 0.f;
        Abuf[(size_t)row * KP + c] = f2bf(v);
    }
}

// Wt[n][k] = out_W[k][n], 256 x 1088 bf16
__global__ __launch_bounds__(256) void k_prepw(const float* __restrict__ Wo,
                                               ushort_t* __restrict__ Wt)
{
    const int n = blockIdx.x;
    for (int k = threadIdx.x; k < KP; k += 256) {
        const float v = (n < H && k < 1076) ? Wo[(size_t)k * H + n] : 0.f;
        Wt[(size_t)n * KP + k] = f2bf(v);
    }
}

// Wpq[n][k]: n<250 -> core_W[k][n] (P); 256<=n<506 -> core_W[250+k][n-256] (Q)
__global__ __launch_bounds__(256) void k_prep_wpq(const float* __restrict__ coreW,
                                                  ushort_t* __restrict__ Wpq)
{
    const int n = blockIdx.x;   // 0..511
    const int k = threadIdx.x;  // 0..255
    float v = 0.f;
    if (k < H) {
        if (n < H)                    v = coreW[(size_t)k * H + n];
        else if (n >= 256 && n < 506) v = coreW[(size_t)(H + k) * H + (n - 256)];
    }
    Wpq[(size_t)n * 256 + k] = f2bf(v);
}

// Wca[n][k]: n<250 -> ctxW[k][n]; 250<=n<350 -> attW1[k][n-250]
__global__ __launch_bounds__(256) void k_prep_wca(const float* __restrict__ ctxW,
                                                  const float* __restrict__ attW1,
                                                  ushort_t* __restrict__ Wca)
{
    const int n = blockIdx.x;   // 0..383
    const int k = threadIdx.x;  // 0..255
    float v = 0.f;
    if (k < H) {
        if (n < H)           v = ctxW[(size_t)k * H + n];
        else if (n < H + HA) v = attW1[(size_t)k * HA + (n - H)];
    }
    Wca[(size_t)n * 256 + k] = f2bf(v);
}

extern "C" void kernel_launch(void* const* d_in, const int* in_sizes, int n_in,
                              void* d_out, int out_size, void* d_ws, size_t ws_size,
                              hipStream_t stream)
{
    const float* x      = (const float*)d_in[0];
    const float* state  = (const float*)d_in[1];
    const float* enc_W  = (const float*)d_in[2];
    const float* enc_b  = (const float*)d_in[3];
    const float* enc_g  = (const float*)d_in[4];
    const float* enc_bt = (const float*)d_in[5];
    const float* core_W = (const float*)d_in[6];
    const float* core_b = (const float*)d_in[7];
    const float* core_g = (const float*)d_in[8];
    const float* core_bt= (const float*)d_in[9];
    const float* ctx_W  = (const float*)d_in[10];
    const float* ctx_b  = (const float*)d_in[11];
    const float* ctx_g  = (const float*)d_in[12];
    const float* ctx_bt = (const float*)d_in[13];
    const float* att_W1 = (const float*)d_in[14];
    const float* att_b1 = (const float*)d_in[15];
    const float* att_g  = (const float*)d_in[16];
    const float* att_bt = (const float*)d_in[17];
    const float* att_W2 = (const float*)d_in[18];
    const float* att_b2 = (const float*)d_in[19];
    const float* out_W  = (const float*)d_in[20];
    const float* out_b  = (const float*)d_in[21];
    float* out = (float*)d_out;

    float* PQ       = (float*)d_ws;                        // 16384*512 f32
    ushort_t* Abuf  = (ushort_t*)(PQ + (size_t)ROWS * PQS);// 16384*1088 bf16
    ushort_t* Wt    = Abuf + (size_t)ROWS * KP;            // 256*1088
    ushort_t* Wpq   = Wt + (size_t)256 * KP;               // 512*256
    ushort_t* Wca   = Wpq + (size_t)512 * 256;             // 384*256
    float* Gstats   = (float*)(Wca + (size_t)384 * 256);   // 114688*2 f32

    k_prepw  <<<256, 256, 0, stream>>>(out_W, Wt);
    k_prep_wpq<<<512, 256, 0, stream>>>(core_W, Wpq);
    k_prep_wca<<<384, 256, 0, stream>>>(ctx_W, att_W1, Wca);
    k_prepx  <<<ROWS, 256, 0, stream>>>(x, Abuf);
    k_enc    <<<ROWS / 32, 256, 0, stream>>>(state, enc_W, enc_b, enc_g, enc_bt, Abuf);
    // PQ = s1 @ [W_top | W_bot]  (bf16 MFMA)
    k_gemm   <<<(ROWS / 64) * 8, 256, 0, stream>>>(Abuf, KP, Wpq, 256, PQ, PQS,
                                                   nullptr, 8, 8, 512);
    k_stats  <<<PROWS / 4, 256, 0, stream>>>(PQ, core_b, Gstats);
    k_ca     <<<ROWS / GCA, 512, 0, stream>>>(PQ, Gstats, core_b, core_g, core_bt, Wca,
                                              ctx_b, ctx_g, ctx_bt,
                                              att_b1, att_g, att_bt, att_W2, att_b2,
                                              Abuf);
    // out = [s1 | eff | x] @ out_W + b  (bf16 MFMA)
    k_gemm   <<<(ROWS / 64) * 4, 256, 0, stream>>>(Abuf, KP, Wt, KP, out, H,
                                                   out_b, KP / 32, 4, H);
}

// Round 6
// 401.877 us; speedup vs baseline: 1.5225x; 1.5225x over previous
//
#include <hip/hip_runtime.h>
#include <math.h>

#define KK 8
#define H 250          // SIZE == h1
#define MDIM 576
#define NB 2048
#define HA 100
#define ROWS (NB*KK)   // 16384
#define PROWS (ROWS*7) // 114688 pair rows
#define PQS 512        // PQb row stride (ushort): P at 0..249, Q at 256..505
#define KP 1088        // padded K for out GEMM (1076 -> 34*32)
#define CSLD 352       // Cs row stride (ushort): 250 ctx + 100 att + 2 pad
#define EPS 1e-5f

typedef unsigned short ushort_t;
typedef short short8 __attribute__((ext_vector_type(8)));
typedef unsigned short us8 __attribute__((ext_vector_type(8)));
typedef unsigned short us4 __attribute__((ext_vector_type(4)));
typedef float f32x4 __attribute__((ext_vector_type(4)));

__device__ __forceinline__ void wave_reduce2(float& a, float& b) {
#pragma unroll
    for (int m = 1; m < 64; m <<= 1) {
        a += __shfl_xor(a, m, 64);
        b += __shfl_xor(b, m, 64);
    }
}
__device__ __forceinline__ float wave_reduce1(float a) {
#pragma unroll
    for (int m = 1; m < 64; m <<= 1) a += __shfl_xor(a, m, 64);
    return a;
}

__device__ __forceinline__ void async_copy16(const void* g, void* l) {
    __builtin_amdgcn_global_load_lds(
        (const __attribute__((address_space(1))) void*)g,
        (__attribute__((address_space(3))) void*)l, 16, 0, 0);
}

__device__ __forceinline__ ushort_t f2bf(float v) {
    union { float f; unsigned int u; } c; c.f = v;
    unsigned int x = c.u;
    x += 0x7fff + ((x >> 16) & 1);   // RNE
    return (ushort_t)(x >> 16);
}
__device__ __forceinline__ float bf2f(ushort_t v) {
    union { unsigned int u; float f; } c; c.u = ((unsigned int)v) << 16;
    return c.f;
}

// s1 = LN(relu(state @ enc_W + enc_b)) -> Abuf cols [0,250) bf16
__global__ __launch_bounds__(256) void k_enc(const float* __restrict__ state,
    const float* __restrict__ W, const float* __restrict__ bias,
    const float* __restrict__ gam, const float* __restrict__ bet,
    ushort_t* __restrict__ Abuf)
{
    __shared__ __align__(16) float st[4][H][8];   // [wave][k][row]
    const int wave = threadIdx.x >> 6, lane = threadIdx.x & 63;
    const int row0 = (blockIdx.x * 4 + wave) * 8;

#pragma unroll
    for (int r = 0; r < 8; ++r)
        for (int kk = lane; kk < H; kk += 64)
            st[wave][kk][r] = state[(size_t)(row0 + r) * H + kk];
    __syncthreads();

    int c[4]; bool val[4]; const float* pW[4];
#pragma unroll
    for (int u = 0; u < 4; ++u) {
        c[u] = lane + 64 * u; val[u] = c[u] < H;
        pW[u] = W + (val[u] ? c[u] : 0);
    }
    float acc[8][4] = {};
    for (int kk = 0; kk < H; ++kk) {
        const float4 sA = *(const float4*)&st[wave][kk][0];
        const float4 sB = *(const float4*)&st[wave][kk][4];
        const float s[8] = {sA.x,sA.y,sA.z,sA.w,sB.x,sB.y,sB.z,sB.w};
        float w[4];
#pragma unroll
        for (int u = 0; u < 4; ++u) { w[u] = *pW[u]; pW[u] += H; }
#pragma unroll
        for (int u = 0; u < 4; ++u)
#pragma unroll
            for (int r = 0; r < 8; ++r)
                acc[r][u] = fmaf(s[r], w[u], acc[r][u]);
    }

    float bv[4], gv[4], btv[4];
#pragma unroll
    for (int u = 0; u < 4; ++u) {
        bv[u]  = val[u] ? bias[c[u]] : 0.f;
        gv[u]  = val[u] ? gam[c[u]]  : 0.f;
        btv[u] = val[u] ? bet[c[u]]  : 0.f;
    }
#pragma unroll
    for (int r = 0; r < 8; ++r) {
        float y[4]; float sm = 0.f, sq = 0.f;
#pragma unroll
        for (int u = 0; u < 4; ++u) {
            float z = val[u] ? fmaxf(acc[r][u] + bv[u], 0.f) : 0.f;
            y[u] = z; sm += z; sq += z * z;
        }
        wave_reduce2(sm, sq);
        const float mu = sm * (1.f / H);
        const float rs = rsqrtf(sq * (1.f / H) - mu * mu + EPS);
#pragma unroll
        for (int u = 0; u < 4; ++u) if (val[u]) {
            const float o = (y[u] - mu) * rs * gv[u] + btv[u];
            Abuf[(size_t)(row0 + r) * KP + c[u]] = f2bf(o);
        }
    }
}

// generic bf16 MFMA GEMM: C[m][n] = sum_k A[m][k]*B[n][k] (+bias[n]);
// fp32 or bf16 output.
__global__ __launch_bounds__(256) void k_gemm(
    const ushort_t* __restrict__ A, int lda,
    const ushort_t* __restrict__ B, int ldb,
    void* __restrict__ Cp, int ldc,
    const float* __restrict__ bias,
    int ksteps, int ntiles, int nlim, int bf16out)
{
    __shared__ __align__(16) ushort_t As[64 * 32];
    __shared__ __align__(16) ushort_t Bs[64 * 32];
    const int tid  = threadIdx.x;
    const int lane = tid & 63, wave = tid >> 6;
    const int wm = wave >> 1, wn = wave & 1;
    const int m0 = ((int)blockIdx.x / ntiles) * 64;
    const int n0 = ((int)blockIdx.x % ntiles) * 64;

    const int srow = tid >> 2;
    const int cs   = tid & 3;
    const int cl   = cs ^ ((srow >> 1) & 3);
    const ushort_t* gA = A + (size_t)(m0 + srow) * lda + cl * 8;
    const ushort_t* gB = B + (size_t)(n0 + srow) * ldb + cl * 8;
    ushort_t* lA = &As[tid * 8];
    ushort_t* lB = &Bs[tid * 8];

    const int q  = lane >> 4;
    const int fr = lane & 15;
    int aoff[2], boff[2];
#pragma unroll
    for (int s = 0; s < 2; ++s) {
        const int ra = wm * 32 + s * 16 + fr;
        aoff[s] = (ra * 4 + (q ^ ((ra >> 1) & 3))) * 8;
        const int rb = wn * 32 + s * 16 + fr;
        boff[s] = (rb * 4 + (q ^ ((rb >> 1) & 3))) * 8;
    }

    f32x4 acc[2][2] = {};
    for (int ks = 0; ks < ksteps; ++ks) {
        const int k0 = ks * 32;
        async_copy16(gA + k0, lA);
        async_copy16(gB + k0, lB);
        __syncthreads();
        short8 a[2], b[2];
#pragma unroll
        for (int s = 0; s < 2; ++s) {
            a[s] = *(const short8*)&As[aoff[s]];
            b[s] = *(const short8*)&Bs[boff[s]];
        }
#pragma unroll
        for (int ms = 0; ms < 2; ++ms)
#pragma unroll
            for (int ns = 0; ns < 2; ++ns)
                acc[ms][ns] = __builtin_amdgcn_mfma_f32_16x16x32_bf16(
                    a[ms], b[ns], acc[ms][ns], 0, 0, 0);
        __syncthreads();
    }

#pragma unroll
    for (int ms = 0; ms < 2; ++ms)
#pragma unroll
        for (int ns = 0; ns < 2; ++ns) {
            const int n_abs = n0 + wn * 32 + ns * 16 + fr;
            if (n_abs >= nlim) continue;
            const float bv = bias ? bias[n_abs] : 0.f;
#pragma unroll
            for (int reg = 0; reg < 4; ++reg) {
                const int m_abs = m0 + wm * 32 + ms * 16 + q * 4 + reg;
                const float v = acc[ms][ns][reg] + bv;
                if (bf16out) ((ushort_t*)Cp)[(size_t)m_abs * ldc + n_abs] = f2bf(v);
                else         ((float*)Cp)[(size_t)m_abs * ldc + n_abs] = v;
            }
        }
}

// Per-pair-row LN stats of relu(P+Q+core_b). One wave per GROUP (P loaded once).
__global__ __launch_bounds__(256) void k_stats(const ushort_t* __restrict__ PQb,
    const float* __restrict__ core_b, float* __restrict__ Gstats)
{
    const int wave = threadIdx.x >> 6, lane = threadIdx.x & 63;
    const int g = blockIdx.x * 4 + wave;        // group 0..16383
    const int i = g & 7;
    const int c = lane * 4;

    const us4 pu = *(const us4*)&PQb[(size_t)g * PQS + c];
    float pe[4], cb[4]; bool vl[4];
#pragma unroll
    for (int t = 0; t < 4; ++t) {
        vl[t] = (c + t) < H;
        pe[t] = bf2f(pu[t]);
        cb[t] = vl[t] ? core_b[c + t] : 0.f;
    }
#pragma unroll 1
    for (int jj = 0; jj < 7; ++jj) {
        const int j = jj + (jj >= i ? 1 : 0);
        const int qr = (g & ~7) + j;
        const us4 qu = *(const us4*)&PQb[(size_t)qr * PQS + 256 + c];
        float sm = 0.f, sq = 0.f;
#pragma unroll
        for (int t = 0; t < 4; ++t) {
            const float z = vl[t] ? fmaxf(pe[t] + bf2f(qu[t]) + cb[t], 0.f) : 0.f;
            sm += z; sq += z * z;
        }
        wave_reduce2(sm, sq);
        if (lane == 0) {
            const int r = g * 7 + jj;
            const float mu = sm * (1.f / H);
            Gstats[r * 2]     = mu;
            Gstats[r * 2 + 1] = rsqrtf(sq * (1.f / H) - mu * mu + EPS);
        }
    }
}

// Cs[r][0:350] = LN(relu(P+Q+b))_r @ [ctxW|attW1]  (bf16 out)
// M=64 rows/block, N=384 resident (A recomputed once per k-step). 256 thr, 4 waves 2x2.
__global__ __launch_bounds__(256) void k_cs(
    const ushort_t* __restrict__ PQb, const float* __restrict__ Gstats,
    const float* __restrict__ core_b, const float* __restrict__ core_g,
    const float* __restrict__ core_bt,
    const ushort_t* __restrict__ Wca,   // [384][256] bf16
    ushort_t* __restrict__ Cs)
{
    __shared__ __align__(16) ushort_t As[64 * 32];    // 4096 B
    __shared__ __align__(16) ushort_t Bs[384 * 32];   // 24576 B
    const int tid = threadIdx.x, lane = tid & 63, wave = tid >> 6;
    const int wm = wave >> 1, wn = wave & 1;
    const int R0 = (int)blockIdx.x * 64;

    // A-staging: thread -> (row ar, chunk acb)
    const int ar  = tid >> 2, acb = tid & 3;
    const int R   = R0 + ar;
    const int g   = R / 7, jj = R - g * 7;
    const int i   = g & 7;
    const int j   = jj + (jj >= i ? 1 : 0);
    const int qr  = (g & ~7) + j;
    const float mu = Gstats[(size_t)R * 2];
    const float rs = Gstats[(size_t)R * 2 + 1];
    const int apos = (ar * 4 + (acb ^ ((ar >> 1) & 3))) * 8;

    const int q = lane >> 4, fr = lane & 15;

    f32x4 acc[2][12] = {};
    for (int ks = 0; ks < 8; ++ks) {
        const int k0 = ks * 32;
        // A: recompute core_out bf16 slice
        {
            const int kc = k0 + acb * 8;
            const us8 pu = *(const us8*)&PQb[(size_t)g  * PQS + kc];
            const us8 qu = *(const us8*)&PQb[(size_t)qr * PQS + 256 + kc];
            short8 ob;
#pragma unroll
            for (int e = 0; e < 8; ++e) {
                const int kk = kc + e;
                float v = 0.f;
                if (kk < H) {
                    const float z = fmaxf(bf2f(pu[e]) + bf2f(qu[e]) + core_b[kk], 0.f);
                    v = (z - mu) * rs * core_g[kk] + core_bt[kk];
                }
                ob[e] = (short)f2bf(v);
            }
            *(short8*)&As[apos] = ob;
        }
        // B: async global->LDS, 1536 chunks over 256 threads
#pragma unroll
        for (int it = 0; it < 6; ++it) {
            const int ci  = it * 256 + tid;
            const int rb  = ci >> 2, cb2 = ci & 3;
            const int clb = cb2 ^ ((rb >> 1) & 3);
            async_copy16(Wca + (size_t)rb * 256 + k0 + clb * 8, &Bs[ci * 8]);
        }
        __syncthreads();
        short8 a[2];
#pragma unroll
        for (int ms = 0; ms < 2; ++ms) {
            const int row = wm * 32 + ms * 16 + fr;
            a[ms] = *(const short8*)&As[(row * 4 + (q ^ ((row >> 1) & 3))) * 8];
        }
#pragma unroll
        for (int nt = 0; nt < 12; ++nt) {
            const int n = wn * 192 + nt * 16 + fr;
            const short8 b = *(const short8*)&Bs[(n * 4 + (q ^ ((n >> 1) & 3))) * 8];
#pragma unroll
            for (int ms = 0; ms < 2; ++ms)
                acc[ms][nt] = __builtin_amdgcn_mfma_f32_16x16x32_bf16(
                    a[ms], b, acc[ms][nt], 0, 0, 0);
        }
        __syncthreads();
    }

    // epilogue: bf16 store
#pragma unroll
    for (int ms = 0; ms < 2; ++ms)
#pragma unroll
        for (int nt = 0; nt < 12; ++nt) {
            const int col = wn * 192 + nt * 16 + fr;
            if (col >= CSLD) continue;
#pragma unroll
            for (int reg = 0; reg < 4; ++reg) {
                const int row = R0 + wm * 32 + ms * 16 + q * 4 + reg;
                Cs[(size_t)row * CSLD + col] = f2bf(acc[ms][nt][reg]);
            }
        }
}

// eff[g] = sum_j sigmoid(att(row)) * LN_ctx(row), rows = Cs[g*7..g*7+6]
// One wave per group; writes bf16 into Abuf cols [250,500).
__global__ __launch_bounds__(256) void k_eff(const ushort_t* __restrict__ Cs,
    const float* __restrict__ ctx_b, const float* __restrict__ ctx_g, const float* __restrict__ ctx_bt,
    const float* __restrict__ att_b1, const float* __restrict__ att_g, const float* __restrict__ att_bt,
    const float* __restrict__ attW2, const float* __restrict__ att_b2,
    ushort_t* __restrict__ Abuf)
{
    const int wave = threadIdx.x >> 6, lane = threadIdx.x & 63;
    const int g = blockIdx.x * 4 + wave;

    float xb[6], xg[6], xbt[6], w2[6]; bool isC[6], isA[6];
#pragma unroll
    for (int u = 0; u < 6; ++u) {
        const int cc = lane + 64 * u;
        isC[u] = cc < H;
        isA[u] = (cc >= H) && (cc < H + HA);
        if (isC[u])      { xb[u] = ctx_b[cc]; xg[u] = ctx_g[cc]; xbt[u] = ctx_bt[cc]; w2[u] = 0.f; }
        else if (isA[u]) { const int ca = cc - H;
                           xb[u] = att_b1[ca]; xg[u] = att_g[ca]; xbt[u] = att_bt[ca]; w2[u] = attW2[ca]; }
        else             { xb[u] = xg[u] = xbt[u] = w2[u] = 0.f; }
    }
    const float ab2 = att_b2[0];
    float effa[4] = {0.f, 0.f, 0.f, 0.f};

#pragma unroll 1
    for (int jj = 0; jj < 7; ++jj) {
        const size_t base = ((size_t)g * 7 + jj) * CSLD;
        float sv[6];
        float smc = 0.f, sqc = 0.f, sma = 0.f, sqa = 0.f;
#pragma unroll
        for (int u = 0; u < 6; ++u) {
            const int cc = lane + 64 * u;
            const float v = (isC[u] || isA[u]) ? bf2f(Cs[base + cc]) : 0.f;
            if (isC[u]) {
                const float z = fmaxf(v + xb[u], 0.f);
                sv[u] = z; smc += z; sqc += z * z;
            } else if (isA[u]) {
                const float za = tanhf(v + xb[u]);
                sv[u] = za; sma += za; sqa += za * za;
            } else sv[u] = 0.f;
        }
        wave_reduce2(smc, sqc);
        wave_reduce2(sma, sqa);
        const float muC = smc * (1.f / H);
        const float rsC = rsqrtf(sqc * (1.f / H) - muC * muC + EPS);
        const float muA = sma * (1.f / HA);
        const float rsA = rsqrtf(sqa * (1.f / HA) - muA * muA + EPS);
        float dot = 0.f;
#pragma unroll
        for (int u = 0; u < 6; ++u) {
            if (isA[u]) {
                const float ath = (sv[u] - muA) * rsA * xg[u] + xbt[u];
                dot += ath * w2[u];
            }
        }
        dot = wave_reduce1(dot);
        const float ag = 1.f / (1.f + expf(-(dot + ab2)));
#pragma unroll
        for (int u = 0; u < 4; ++u) {
            if (isC[u]) {
                const float ctxo = (sv[u] - muC) * rsC * xg[u] + xbt[u];
                effa[u] = fmaf(ag, ctxo, effa[u]);
            }
        }
    }
#pragma unroll
    for (int u = 0; u < 4; ++u) {
        const int cc = lane + 64 * u;
        if (isC[u]) Abuf[(size_t)g * KP + H + cc] = f2bf(effa[u]);
    }
}

// Abuf cols [500,1088): x (bf16) + zero pad
__global__ __launch_bounds__(256) void k_prepx(const float* __restrict__ x,
                                               ushort_t* __restrict__ Abuf)
{
    const int row = blockIdx.x;
    for (int c = 500 + threadIdx.x; c < KP; c += 256) {
        const float v = (c < 500 + MDIM) ? x[(size_t)row * MDIM + (c - 500)] : 0.f;
        Abuf[(size_t)row * KP + c] = f2bf(v);
    }
}

// Wt[n][k] = out_W[k][n], 256 x 1088 bf16
__global__ __launch_bounds__(256) void k_prepw(const float* __restrict__ Wo,
                                               ushort_t* __restrict__ Wt)
{
    const int n = blockIdx.x;
    for (int k = threadIdx.x; k < KP; k += 256) {
        const float v = (n < H && k < 1076) ? Wo[(size_t)k * H + n] : 0.f;
        Wt[(size_t)n * KP + k] = f2bf(v);
    }
}

// Wpq[n][k]: n<250 -> core_W[k][n] (P); 256<=n<506 -> core_W[250+k][n-256] (Q)
__global__ __launch_bounds__(256) void k_prep_wpq(const float* __restrict__ coreW,
                                                  ushort_t* __restrict__ Wpq)
{
    const int n = blockIdx.x;   // 0..511
    const int k = threadIdx.x;  // 0..255
    float v = 0.f;
    if (k < H) {
        if (n < H)                    v = coreW[(size_t)k * H + n];
        else if (n >= 256 && n < 506) v = coreW[(size_t)(H + k) * H + (n - 256)];
    }
    Wpq[(size_t)n * 256 + k] = f2bf(v);
}

// Wca[n][k]: n<250 -> ctxW[k][n]; 250<=n<350 -> attW1[k][n-250]
__global__ __launch_bounds__(256) void k_prep_wca(const float* __restrict__ ctxW,
                                                  const float* __restrict__ attW1,
                                                  ushort_t* __restrict__ Wca)
{
    const int n = blockIdx.x;   // 0..383
    const int k = threadIdx.x;  // 0..255
    float v = 0.f;
    if (k < H) {
        if (n < H)           v = ctxW[(size_t)k * H + n];
        else if (n < H + HA) v = attW1[(size_t)k * HA + (n - H)];
    }
    Wca[(size_t)n * 256 + k] = f2bf(v);
}

extern "C" void kernel_launch(void* const* d_in, const int* in_sizes, int n_in,
                              void* d_out, int out_size, void* d_ws, size_t ws_size,
                              hipStream_t stream)
{
    const float* x      = (const float*)d_in[0];
    const float* state  = (const float*)d_in[1];
    const float* enc_W  = (const float*)d_in[2];
    const float* enc_b  = (const float*)d_in[3];
    const float* enc_g  = (const float*)d_in[4];
    const float* enc_bt = (const float*)d_in[5];
    const float* core_W = (const float*)d_in[6];
    const float* core_b = (const float*)d_in[7];
    const float* core_g = (const float*)d_in[8];
    const float* core_bt= (const float*)d_in[9];
    const float* ctx_W  = (const float*)d_in[10];
    const float* ctx_b  = (const float*)d_in[11];
    const float* ctx_g  = (const float*)d_in[12];
    const float* ctx_bt = (const float*)d_in[13];
    const float* att_W1 = (const float*)d_in[14];
    const float* att_b1 = (const float*)d_in[15];
    const float* att_g  = (const float*)d_in[16];
    const float* att_bt = (const float*)d_in[17];
    const float* att_W2 = (const float*)d_in[18];
    const float* att_b2 = (const float*)d_in[19];
    const float* out_W  = (const float*)d_in[20];
    const float* out_b  = (const float*)d_in[21];
    float* out = (float*)d_out;

    ushort_t* Abuf = (ushort_t*)d_ws;                   // 16384*1088 bf16 (35.7 MB)
    ushort_t* Wt   = Abuf + (size_t)ROWS * KP;          // 256*1088
    ushort_t* Wpq  = Wt + (size_t)256 * KP;             // 512*256
    ushort_t* Wca  = Wpq + (size_t)512 * 256;           // 384*256
    ushort_t* PQb  = Wca + (size_t)384 * 256;           // 16384*512 bf16 (16.8 MB)
    float* Gstats  = (float*)(PQb + (size_t)ROWS * PQS);// 114688*2 f32 (0.9 MB)
    ushort_t* Cs   = (ushort_t*)(Gstats + (size_t)PROWS * 2); // 114688*352 bf16 (80.7 MB)

    k_prepw   <<<256, 256, 0, stream>>>(out_W, Wt);
    k_prep_wpq<<<512, 256, 0, stream>>>(core_W, Wpq);
    k_prep_wca<<<384, 256, 0, stream>>>(ctx_W, att_W1, Wca);
    k_prepx   <<<ROWS, 256, 0, stream>>>(x, Abuf);
    k_enc     <<<ROWS / 32, 256, 0, stream>>>(state, enc_W, enc_b, enc_g, enc_bt, Abuf);
    // PQb = s1 @ [W_top | W_bot]  (bf16 MFMA, bf16 out)
    k_gemm    <<<(ROWS / 64) * 8, 256, 0, stream>>>(Abuf, KP, Wpq, 256, PQb, PQS,
                                                    nullptr, 8, 8, 512, 1);
    k_stats   <<<ROWS / 4, 256, 0, stream>>>(PQb, core_b, Gstats);
    k_cs      <<<PROWS / 64, 256, 0, stream>>>(PQb, Gstats, core_b, core_g, core_bt,
                                               Wca, Cs);
    k_eff     <<<ROWS / 4, 256, 0, stream>>>(Cs, ctx_b, ctx_g, ctx_bt,
                                             att_b1, att_g, att_bt, att_W2, att_b2,
                                             Abuf);
    // out = [s1 | eff | x] @ out_W + b  (bf16 MFMA, fp32 out)
    k_gemm    <<<(ROWS / 64) * 4, 256, 0, stream>>>(Abuf, KP, Wt, KP, out, H,
                                                    out_b, KP / 32, 4, H, 0);
}

// Round 7
// 375.576 us; speedup vs baseline: 1.6291x; 1.0700x over previous
//
#include <hip/hip_runtime.h>
#include <math.h>

#define KK 8
#define H 250          // SIZE == h1
#define MDIM 576
#define NB 2048
#define HA 100
#define ROWS (NB*KK)   // 16384
#define PROWS (ROWS*7) // 114688 pair rows
#define PQS 512        // PQb row stride (ushort): P at 0..249, Q at 256..505
#define KP 1088        // padded K for out GEMM (1076 -> 34*32)
#define CSLD 352       // Cs row stride (ushort): 250 ctx + 100 att + 2 pad
#define EPS 1e-5f

typedef unsigned short ushort_t;
typedef short short8 __attribute__((ext_vector_type(8)));
typedef unsigned short us8 __attribute__((ext_vector_type(8)));
typedef unsigned short us4 __attribute__((ext_vector_type(4)));
typedef unsigned short us2 __attribute__((ext_vector_type(2)));
typedef float f32x4 __attribute__((ext_vector_type(4)));

__device__ __forceinline__ void wave_reduce2(float& a, float& b) {
#pragma unroll
    for (int m = 1; m < 64; m <<= 1) {
        a += __shfl_xor(a, m, 64);
        b += __shfl_xor(b, m, 64);
    }
}
__device__ __forceinline__ float wave_reduce1(float a) {
#pragma unroll
    for (int m = 1; m < 64; m <<= 1) a += __shfl_xor(a, m, 64);
    return a;
}

__device__ __forceinline__ void async_copy16(const void* g, void* l) {
    __builtin_amdgcn_global_load_lds(
        (const __attribute__((address_space(1))) void*)g,
        (__attribute__((address_space(3))) void*)l, 16, 0, 0);
}

__device__ __forceinline__ ushort_t f2bf(float v) {
    union { float f; unsigned int u; } c; c.f = v;
    unsigned int x = c.u;
    x += 0x7fff + ((x >> 16) & 1);   // RNE
    return (ushort_t)(x >> 16);
}
__device__ __forceinline__ float bf2f(ushort_t v) {
    union { unsigned int u; float f; } c; c.u = ((unsigned int)v) << 16;
    return c.f;
}

// ---- fused prep: Wt | Wpq | Wca | Wenc | Sb | x->Abuf ----
__global__ __launch_bounds__(256) void k_prep(
    const float* __restrict__ out_W, const float* __restrict__ core_W,
    const float* __restrict__ ctx_W, const float* __restrict__ att_W1,
    const float* __restrict__ enc_W, const float* __restrict__ state,
    const float* __restrict__ x,
    ushort_t* __restrict__ Wt, ushort_t* __restrict__ Wpq,
    ushort_t* __restrict__ Wca, ushort_t* __restrict__ Wenc,
    ushort_t* __restrict__ Sb, ushort_t* __restrict__ Abuf)
{
    const int b = blockIdx.x, t = threadIdx.x;
    if (b < 256) {                      // Wt[n][k] = out_W[k][n]
        const int n = b;
        for (int k = t; k < KP; k += 256) {
            const float v = (n < H && k < 1076) ? out_W[(size_t)k * H + n] : 0.f;
            Wt[(size_t)n * KP + k] = f2bf(v);
        }
    } else if (b < 768) {               // Wpq
        const int n = b - 256, k = t;
        float v = 0.f;
        if (k < H) {
            if (n < H)                    v = core_W[(size_t)k * H + n];
            else if (n >= 256 && n < 506) v = core_W[(size_t)(H + k) * H + (n - 256)];
        }
        Wpq[(size_t)n * 256 + k] = f2bf(v);
    } else if (b < 1152) {              // Wca
        const int n = b - 768, k = t;
        float v = 0.f;
        if (k < H) {
            if (n < H)           v = ctx_W[(size_t)k * H + n];
            else if (n < H + HA) v = att_W1[(size_t)k * HA + (n - H)];
        }
        Wca[(size_t)n * 256 + k] = f2bf(v);
    } else if (b < 1408) {              // Wenc[n][k] = enc_W[k][n]
        const int n = b - 1152, k = t;
        const float v = (n < H && k < H) ? enc_W[(size_t)k * H + n] : 0.f;
        Wenc[(size_t)n * 256 + k] = f2bf(v);
    } else if (b < 2432) {              // Sb: state padded to 256, bf16
        const int r0 = (b - 1408) * 16;
        for (int idx = t; idx < 16 * 256; idx += 256) {
            const int r = r0 + (idx >> 8), k = idx & 255;
            const float v = (k < H) ? state[(size_t)r * H + k] : 0.f;
            Sb[(size_t)r * 256 + k] = f2bf(v);
        }
    } else {                            // Abuf cols [500,1088): x + pad
        const int row = b - 2432;
        for (int c = 500 + t; c < KP; c += 256) {
            const float v = (c < 500 + MDIM) ? x[(size_t)row * MDIM + (c - 500)] : 0.f;
            Abuf[(size_t)row * KP + c] = f2bf(v);
        }
    }
}

// generic bf16 MFMA GEMM: C[m][n] = sum_k A[m][k]*B[n][k] (+bias[n]); f32/bf16 out
__global__ __launch_bounds__(256) void k_gemm(
    const ushort_t* __restrict__ A, int lda,
    const ushort_t* __restrict__ B, int ldb,
    void* __restrict__ Cp, int ldc,
    const float* __restrict__ bias,
    int ksteps, int ntiles, int nlim, int bf16out)
{
    __shared__ __align__(16) ushort_t As[64 * 32];
    __shared__ __align__(16) ushort_t Bs[64 * 32];
    const int tid  = threadIdx.x;
    const int lane = tid & 63, wave = tid >> 6;
    const int wm = wave >> 1, wn = wave & 1;
    const int m0 = ((int)blockIdx.x / ntiles) * 64;
    const int n0 = ((int)blockIdx.x % ntiles) * 64;

    const int srow = tid >> 2;
    const int cs   = tid & 3;
    const int cl   = cs ^ ((srow >> 1) & 3);
    const ushort_t* gA = A + (size_t)(m0 + srow) * lda + cl * 8;
    const ushort_t* gB = B + (size_t)(n0 + srow) * ldb + cl * 8;
    ushort_t* lA = &As[tid * 8];
    ushort_t* lB = &Bs[tid * 8];

    const int q  = lane >> 4;
    const int fr = lane & 15;
    int aoff[2], boff[2];
#pragma unroll
    for (int s = 0; s < 2; ++s) {
        const int ra = wm * 32 + s * 16 + fr;
        aoff[s] = (ra * 4 + (q ^ ((ra >> 1) & 3))) * 8;
        const int rb = wn * 32 + s * 16 + fr;
        boff[s] = (rb * 4 + (q ^ ((rb >> 1) & 3))) * 8;
    }

    f32x4 acc[2][2] = {};
    for (int ks = 0; ks < ksteps; ++ks) {
        const int k0 = ks * 32;
        async_copy16(gA + k0, lA);
        async_copy16(gB + k0, lB);
        __syncthreads();
        short8 a[2], b[2];
#pragma unroll
        for (int s = 0; s < 2; ++s) {
            a[s] = *(const short8*)&As[aoff[s]];
            b[s] = *(const short8*)&Bs[boff[s]];
        }
#pragma unroll
        for (int ms = 0; ms < 2; ++ms)
#pragma unroll
            for (int ns = 0; ns < 2; ++ns)
                acc[ms][ns] = __builtin_amdgcn_mfma_f32_16x16x32_bf16(
                    a[ms], b[ns], acc[ms][ns], 0, 0, 0);
        __syncthreads();
    }

#pragma unroll
    for (int ms = 0; ms < 2; ++ms)
#pragma unroll
        for (int ns = 0; ns < 2; ++ns) {
            const int n_abs = n0 + wn * 32 + ns * 16 + fr;
            if (n_abs >= nlim) continue;
            const float bv = bias ? bias[n_abs] : 0.f;
#pragma unroll
            for (int reg = 0; reg < 4; ++reg) {
                const int m_abs = m0 + wm * 32 + ms * 16 + q * 4 + reg;
                const float v = acc[ms][ns][reg] + bv;
                if (bf16out) ((ushort_t*)Cp)[(size_t)m_abs * ldc + n_abs] = f2bf(v);
                else         ((float*)Cp)[(size_t)m_abs * ldc + n_abs] = v;
            }
        }
}

// LN(relu(Epre + enc_b)) -> Abuf cols [0,250). One wave per row, us4 loads.
__global__ __launch_bounds__(256) void k_lnenc(const ushort_t* __restrict__ Epre,
    const float* __restrict__ eb, const float* __restrict__ eg,
    const float* __restrict__ ebt, ushort_t* __restrict__ Abuf)
{
    const int wave = threadIdx.x >> 6, lane = threadIdx.x & 63;
    const int row = blockIdx.x * 4 + wave;
    const int c0 = 4 * lane;

    const us4 v = *(const us4*)&Epre[(size_t)row * 256 + c0];
    float y[4]; float sm = 0.f, sq = 0.f;
#pragma unroll
    for (int t = 0; t < 4; ++t) {
        const int cc = c0 + t;
        float z = 0.f;
        if (cc < H) z = fmaxf(bf2f(v[t]) + eb[cc], 0.f);
        y[t] = z; sm += z; sq += z * z;
    }
    wave_reduce2(sm, sq);
    const float mu = sm * (1.f / H);
    const float rs = rsqrtf(sq * (1.f / H) - mu * mu + EPS);
    ushort_t o[4];
#pragma unroll
    for (int t = 0; t < 4; ++t) {
        const int cc = c0 + t;
        o[t] = (cc < H) ? f2bf((y[t] - mu) * rs * eg[cc] + ebt[cc]) : (ushort_t)0;
    }
    ushort_t* dst = Abuf + (size_t)row * KP + c0;
    if (c0 + 3 < H) { *(us4*)dst = (us4){o[0], o[1], o[2], o[3]}; }
    else {
        if (c0 + 1 < H) *(us2*)dst = (us2){o[0], o[1]};
    }
}

// Per-pair-row LN stats of relu(P+Q+core_b). One wave per GROUP (P loaded once).
__global__ __launch_bounds__(256) void k_stats(const ushort_t* __restrict__ PQb,
    const float* __restrict__ core_b, float* __restrict__ Gstats)
{
    const int wave = threadIdx.x >> 6, lane = threadIdx.x & 63;
    const int g = blockIdx.x * 4 + wave;        // group 0..16383
    const int i = g & 7;
    const int c = lane * 4;

    const us4 pu = *(const us4*)&PQb[(size_t)g * PQS + c];
    float pe[4], cb[4]; bool vl[4];
#pragma unroll
    for (int t = 0; t < 4; ++t) {
        vl[t] = (c + t) < H;
        pe[t] = bf2f(pu[t]);
        cb[t] = vl[t] ? core_b[c + t] : 0.f;
    }
#pragma unroll 1
    for (int jj = 0; jj < 7; ++jj) {
        const int j = jj + (jj >= i ? 1 : 0);
        const int qr = (g & ~7) + j;
        const us4 qu = *(const us4*)&PQb[(size_t)qr * PQS + 256 + c];
        float sm = 0.f, sq = 0.f;
#pragma unroll
        for (int t = 0; t < 4; ++t) {
            const float z = vl[t] ? fmaxf(pe[t] + bf2f(qu[t]) + cb[t], 0.f) : 0.f;
            sm += z; sq += z * z;
        }
        wave_reduce2(sm, sq);
        if (lane == 0) {
            const int r = g * 7 + jj;
            const float mu = sm * (1.f / H);
            Gstats[r * 2]     = mu;
            Gstats[r * 2 + 1] = rsqrtf(sq * (1.f / H) - mu * mu + EPS);
        }
    }
}

// Cs[r][0:352] = LN(relu(P+Q+b))_r @ [ctxW|attW1]  (bf16 out)
// M=64/block, N=384 resident. 512 threads = 8 waves (2x4); acc[2][6] = 48 AGPR/wave
// -> <=128 total regs (launch_bounds 4 waves/EU) -> 2 blocks/CU (round-6 was 2 waves/SIMD).
__global__ __launch_bounds__(512, 4) void k_cs(
    const ushort_t* __restrict__ PQb, const float* __restrict__ Gstats,
    const float* __restrict__ core_b, const float* __restrict__ core_g,
    const float* __restrict__ core_bt,
    const ushort_t* __restrict__ Wca,   // [384][256] bf16
    ushort_t* __restrict__ Cs)
{
    __shared__ __align__(16) ushort_t As[64 * 32];    // 4096 B
    __shared__ __align__(16) ushort_t Bs[384 * 32];   // 24576 B
    const int tid = threadIdx.x, lane = tid & 63, wave = tid >> 6;
    const int wm = wave >> 2, wn = wave & 3;
    const int R0 = (int)blockIdx.x * 64;

    // A-staging (threads 0..255): thread -> (row ar, chunk acb)
    const int ar = tid >> 2, acb = tid & 3;
    const bool aon = tid < 256;
    int g = 0, qr = 0, apos = 0; float mu = 0.f, rs = 0.f;
    if (aon) {
        const int R = R0 + ar;
        g = R / 7; const int jj = R - g * 7;
        const int i = g & 7;
        const int j = jj + (jj >= i ? 1 : 0);
        qr = (g & ~7) + j;
        mu = Gstats[(size_t)R * 2]; rs = Gstats[(size_t)R * 2 + 1];
        apos = (ar * 4 + (acb ^ ((ar >> 1) & 3))) * 8;
    }
    const int q = lane >> 4, fr = lane & 15;

    f32x4 acc[2][6] = {};
    for (int ks = 0; ks < 8; ++ks) {
        const int k0 = ks * 32;
        if (aon) {
            const int kc = k0 + acb * 8;
            const us8 pu = *(const us8*)&PQb[(size_t)g  * PQS + kc];
            const us8 qu = *(const us8*)&PQb[(size_t)qr * PQS + 256 + kc];
            short8 ob;
#pragma unroll
            for (int e = 0; e < 8; ++e) {
                const int kk = kc + e;
                float v = 0.f;
                if (kk < H) {
                    const float z = fmaxf(bf2f(pu[e]) + bf2f(qu[e]) + core_b[kk], 0.f);
                    v = (z - mu) * rs * core_g[kk] + core_bt[kk];
                }
                ob[e] = (short)f2bf(v);
            }
            *(short8*)&As[apos] = ob;
        }
#pragma unroll
        for (int it = 0; it < 3; ++it) {
            const int ci  = it * 512 + tid;
            const int rb  = ci >> 2, cb2 = ci & 3;
            const int clb = cb2 ^ ((rb >> 1) & 3);
            async_copy16(Wca + (size_t)rb * 256 + k0 + clb * 8, &Bs[ci * 8]);
        }
        __syncthreads();
        short8 a[2];
#pragma unroll
        for (int ms = 0; ms < 2; ++ms) {
            const int row = wm * 32 + ms * 16 + fr;
            a[ms] = *(const short8*)&As[(row * 4 + (q ^ ((row >> 1) & 3))) * 8];
        }
#pragma unroll
        for (int nt = 0; nt < 6; ++nt) {
            const int n = wn * 96 + nt * 16 + fr;
            const short8 b = *(const short8*)&Bs[(n * 4 + (q ^ ((n >> 1) & 3))) * 8];
#pragma unroll
            for (int ms = 0; ms < 2; ++ms)
                acc[ms][nt] = __builtin_amdgcn_mfma_f32_16x16x32_bf16(
                    a[ms], b, acc[ms][nt], 0, 0, 0);
        }
        __syncthreads();
    }

#pragma unroll
    for (int ms = 0; ms < 2; ++ms)
#pragma unroll
        for (int nt = 0; nt < 6; ++nt) {
            const int col = wn * 96 + nt * 16 + fr;
            if (col >= CSLD) continue;
#pragma unroll
            for (int reg = 0; reg < 4; ++reg) {
                const int row = R0 + wm * 32 + ms * 16 + q * 4 + reg;
                Cs[(size_t)row * CSLD + col] = f2bf(acc[ms][nt][reg]);
            }
        }
}

// eff[g] = sum_j sigmoid(att(row)) * LN_ctx(row). One wave per group, vector loads.
__global__ __launch_bounds__(256) void k_eff(const ushort_t* __restrict__ Cs,
    const float* __restrict__ ctx_b, const float* __restrict__ ctx_g, const float* __restrict__ ctx_bt,
    const float* __restrict__ att_b1, const float* __restrict__ att_g, const float* __restrict__ att_bt,
    const float* __restrict__ attW2, const float* __restrict__ att_b2,
    ushort_t* __restrict__ Abuf)
{
    const int wave = threadIdx.x >> 6, lane = threadIdx.x & 63;
    const int g = blockIdx.x * 4 + wave;
    const int c0 = 4 * lane;           // 0..252
    const int c1 = 256 + 2 * lane;     // 256..382, valid while c1+1 < CSLD (lane<48)
    const bool l48 = lane < 48;

    int ce[6]; bool eC[6], eA[6]; float b_[6], g_[6], bt_[6], w2_[6];
#pragma unroll
    for (int e = 0; e < 6; ++e) {
        ce[e] = (e < 4) ? (c0 + e) : (c1 + (e - 4));
        const bool vld = (e < 4) || l48;
        eC[e] = vld && (ce[e] < H);
        eA[e] = vld && (ce[e] >= H) && (ce[e] < H + HA);
        if (eC[e])      { b_[e] = ctx_b[ce[e]]; g_[e] = ctx_g[ce[e]]; bt_[e] = ctx_bt[ce[e]]; w2_[e] = 0.f; }
        else if (eA[e]) { const int ca = ce[e] - H;
                          b_[e] = att_b1[ca]; g_[e] = att_g[ca]; bt_[e] = att_bt[ca]; w2_[e] = attW2[ca]; }
        else            { b_[e] = g_[e] = bt_[e] = w2_[e] = 0.f; }
    }
    const float ab2 = att_b2[0];
    float effa[4] = {0.f, 0.f, 0.f, 0.f};

#pragma unroll 1
    for (int jj = 0; jj < 7; ++jj) {
        const size_t base = ((size_t)g * 7 + jj) * CSLD;
        const us4 v0 = *(const us4*)&Cs[base + c0];
        us2 v1 = {0, 0};
        if (l48) v1 = *(const us2*)&Cs[base + c1];
        float raw[6];
#pragma unroll
        for (int e = 0; e < 4; ++e) raw[e] = bf2f(v0[e]);
        raw[4] = bf2f(v1[0]); raw[5] = bf2f(v1[1]);

        float sv[6]; float smc = 0.f, sqc = 0.f, sma = 0.f, sqa = 0.f;
#pragma unroll
        for (int e = 0; e < 6; ++e) {
            if (eC[e]) {
                const float z = fmaxf(raw[e] + b_[e], 0.f);
                sv[e] = z; smc += z; sqc += z * z;
            } else if (eA[e]) {
                const float za = tanhf(raw[e] + b_[e]);
                sv[e] = za; sma += za; sqa += za * za;
            } else sv[e] = 0.f;
        }
        wave_reduce2(smc, sqc);
        wave_reduce2(sma, sqa);
        const float muC = smc * (1.f / H);
        const float rsC = rsqrtf(sqc * (1.f / H) - muC * muC + EPS);
        const float muA = sma * (1.f / HA);
        const float rsA = rsqrtf(sqa * (1.f / HA) - muA * muA + EPS);
        float dot = 0.f;
#pragma unroll
        for (int e = 0; e < 6; ++e) {
            if (eA[e]) {
                const float ath = (sv[e] - muA) * rsA * g_[e] + bt_[e];
                dot += ath * w2_[e];
            }
        }
        dot = wave_reduce1(dot);
        const float ag = 1.f / (1.f + expf(-(dot + ab2)));
#pragma unroll
        for (int e = 0; e < 4; ++e) {
            if (eC[e]) {
                const float ctxo = (sv[e] - muC) * rsC * g_[e] + bt_[e];
                effa[e] = fmaf(ag, ctxo, effa[e]);
            }
        }
    }
    ushort_t* dst = Abuf + (size_t)g * KP + H + c0;
    if (c0 + 1 < H) *(us2*)dst       = (us2){f2bf(effa[0]), f2bf(effa[1])};
    if (c0 + 3 < H) *(us2*)(dst + 2) = (us2){f2bf(effa[2]), f2bf(effa[3])};
}

extern "C" void kernel_launch(void* const* d_in, const int* in_sizes, int n_in,
                              void* d_out, int out_size, void* d_ws, size_t ws_size,
                              hipStream_t stream)
{
    const float* x      = (const float*)d_in[0];
    const float* state  = (const float*)d_in[1];
    const float* enc_W  = (const float*)d_in[2];
    const float* enc_b  = (const float*)d_in[3];
    const float* enc_g  = (const float*)d_in[4];
    const float* enc_bt = (const float*)d_in[5];
    const float* core_W = (const float*)d_in[6];
    const float* core_b = (const float*)d_in[7];
    const float* core_g = (const float*)d_in[8];
    const float* core_bt= (const float*)d_in[9];
    const float* ctx_W  = (const float*)d_in[10];
    const float* ctx_b  = (const float*)d_in[11];
    const float* ctx_g  = (const float*)d_in[12];
    const float* ctx_bt = (const float*)d_in[13];
    const float* att_W1 = (const float*)d_in[14];
    const float* att_b1 = (const float*)d_in[15];
    const float* att_g  = (const float*)d_in[16];
    const float* att_bt = (const float*)d_in[17];
    const float* att_W2 = (const float*)d_in[18];
    const float* att_b2 = (const float*)d_in[19];
    const float* out_W  = (const float*)d_in[20];
    const float* out_b  = (const float*)d_in[21];
    float* out = (float*)d_out;

    ushort_t* Abuf = (ushort_t*)d_ws;                   // 16384*1088 bf16 (35.7 MB)
    ushort_t* Wt   = Abuf + (size_t)ROWS * KP;          // 256*1088
    ushort_t* Wpq  = Wt + (size_t)256 * KP;             // 512*256
    ushort_t* Wca  = Wpq + (size_t)512 * 256;           // 384*256
    ushort_t* Wenc = Wca + (size_t)384 * 256;           // 256*256
    ushort_t* PQb  = Wenc + (size_t)256 * 256;          // 16384*512 bf16 (16.8 MB)
    float* Gstats  = (float*)(PQb + (size_t)ROWS * PQS);// 114688*2 f32 (0.9 MB)
    ushort_t* Cs   = (ushort_t*)(Gstats + (size_t)PROWS * 2); // 114688*352 bf16 (80.7 MB)
    // Sb/Epre alias the Cs region (both dead before k_cs writes Cs)
    ushort_t* Sb   = Cs;                                // 16384*256 bf16 (8.4 MB)
    ushort_t* Epre = Cs + (size_t)ROWS * 256;           // 16384*256 bf16 (8.4 MB)

    k_prep  <<<2432 + ROWS, 256, 0, stream>>>(out_W, core_W, ctx_W, att_W1, enc_W,
                                              state, x, Wt, Wpq, Wca, Wenc, Sb, Abuf);
    // Epre = state @ enc_W  (bf16 MFMA)
    k_gemm  <<<(ROWS / 64) * 4, 256, 0, stream>>>(Sb, 256, Wenc, 256, Epre, 256,
                                                  nullptr, 8, 4, 256, 1);
    k_lnenc <<<ROWS / 4, 256, 0, stream>>>(Epre, enc_b, enc_g, enc_bt, Abuf);
    // PQb = s1 @ [W_top | W_bot]  (bf16 MFMA, bf16 out)
    k_gemm  <<<(ROWS / 64) * 8, 256, 0, stream>>>(Abuf, KP, Wpq, 256, PQb, PQS,
                                                  nullptr, 8, 8, 512, 1);
    k_stats <<<ROWS / 4, 256, 0, stream>>>(PQb, core_b, Gstats);
    k_cs    <<<PROWS / 64, 512, 0, stream>>>(PQb, Gstats, core_b, core_g, core_bt,
                                             Wca, Cs);
    k_eff   <<<ROWS / 4, 256, 0, stream>>>(Cs, ctx_b, ctx_g, ctx_bt,
                                           att_b1, att_g, att_bt, att_W2, att_b2,
                                           Abuf);
    // out = [s1 | eff | x] @ out_W + b  (bf16 MFMA, fp32 out)
    k_gemm  <<<(ROWS / 64) * 4, 256, 0, stream>>>(Abuf, KP, Wt, KP, out, H,
                                                  out_b, KP / 32, 4, H, 0);
}

// Round 8
// 351.567 us; speedup vs baseline: 1.7403x; 1.0683x over previous
//
#include <hip/hip_runtime.h>
#include <math.h>

#define KK 8
#define H 250          // SIZE == h1
#define MDIM 576
#define NB 2048
#define HA 100
#define ROWS (NB*KK)   // 16384
#define PROWS (ROWS*7) // 114688 pair rows
#define PQS 512        // PQb row stride (ushort): P at 0..249, Q at 256..505
#define KP 1088        // padded K for out GEMM (1076 -> 34*32)
#define CSLD 352       // Cs row stride (ushort): 250 ctx + 100 att + 2 pad
#define EPS 1e-5f

typedef unsigned short ushort_t;
typedef short short8 __attribute__((ext_vector_type(8)));
typedef unsigned short us8 __attribute__((ext_vector_type(8)));
typedef unsigned short us4 __attribute__((ext_vector_type(4)));
typedef unsigned short us2 __attribute__((ext_vector_type(2)));
typedef float f32x4 __attribute__((ext_vector_type(4)));

__device__ __forceinline__ void wave_reduce2(float& a, float& b) {
#pragma unroll
    for (int m = 1; m < 64; m <<= 1) {
        a += __shfl_xor(a, m, 64);
        b += __shfl_xor(b, m, 64);
    }
}
__device__ __forceinline__ float wave_reduce1(float a) {
#pragma unroll
    for (int m = 1; m < 64; m <<= 1) a += __shfl_xor(a, m, 64);
    return a;
}

__device__ __forceinline__ void async_copy16(const void* g, void* l) {
    __builtin_amdgcn_global_load_lds(
        (const __attribute__((address_space(1))) void*)g,
        (__attribute__((address_space(3))) void*)l, 16, 0, 0);
}

__device__ __forceinline__ ushort_t f2bf(float v) {
    union { float f; unsigned int u; } c; c.f = v;
    unsigned int x = c.u;
    x += 0x7fff + ((x >> 16) & 1);   // RNE
    return (ushort_t)(x >> 16);
}
__device__ __forceinline__ float bf2f(ushort_t v) {
    union { unsigned int u; float f; } c; c.u = ((unsigned int)v) << 16;
    return c.f;
}

// ---- fused prep: Wt | Wpq | Wca | Wenc | Sb | x->Abuf ----
__global__ __launch_bounds__(256) void k_prep(
    const float* __restrict__ out_W, const float* __restrict__ core_W,
    const float* __restrict__ ctx_W, const float* __restrict__ att_W1,
    const float* __restrict__ enc_W, const float* __restrict__ state,
    const float* __restrict__ x,
    ushort_t* __restrict__ Wt, ushort_t* __restrict__ Wpq,
    ushort_t* __restrict__ Wca, ushort_t* __restrict__ Wenc,
    ushort_t* __restrict__ Sb, ushort_t* __restrict__ Abuf)
{
    const int b = blockIdx.x, t = threadIdx.x;
    if (b < 256) {                      // Wt[n][k] = out_W[k][n]
        const int n = b;
        for (int k = t; k < KP; k += 256) {
            const float v = (n < H && k < 1076) ? out_W[(size_t)k * H + n] : 0.f;
            Wt[(size_t)n * KP + k] = f2bf(v);
        }
    } else if (b < 768) {               // Wpq
        const int n = b - 256, k = t;
        float v = 0.f;
        if (k < H) {
            if (n < H)                    v = core_W[(size_t)k * H + n];
            else if (n >= 256 && n < 506) v = core_W[(size_t)(H + k) * H + (n - 256)];
        }
        Wpq[(size_t)n * 256 + k] = f2bf(v);
    } else if (b < 1152) {              // Wca
        const int n = b - 768, k = t;
        float v = 0.f;
        if (k < H) {
            if (n < H)           v = ctx_W[(size_t)k * H + n];
            else if (n < H + HA) v = att_W1[(size_t)k * HA + (n - H)];
        }
        Wca[(size_t)n * 256 + k] = f2bf(v);
    } else if (b < 1408) {              // Wenc[n][k] = enc_W[k][n]
        const int n = b - 1152, k = t;
        const float v = (n < H && k < H) ? enc_W[(size_t)k * H + n] : 0.f;
        Wenc[(size_t)n * 256 + k] = f2bf(v);
    } else if (b < 2432) {              // Sb: state padded to 256, bf16
        const int r0 = (b - 1408) * 16;
        for (int idx = t; idx < 16 * 256; idx += 256) {
            const int r = r0 + (idx >> 8), k = idx & 255;
            const float v = (k < H) ? state[(size_t)r * H + k] : 0.f;
            Sb[(size_t)r * 256 + k] = f2bf(v);
        }
    } else {                            // Abuf cols [500,1088): x + pad
        const int row = b - 2432;
        for (int c = 500 + t; c < KP; c += 256) {
            const float v = (c < 500 + MDIM) ? x[(size_t)row * MDIM + (c - 500)] : 0.f;
            Abuf[(size_t)row * KP + c] = f2bf(v);
        }
    }
}

// generic bf16 MFMA GEMM: C[m][n] = sum_k A[m][k]*B[n][k] (+bias[n]); f32/bf16 out
__global__ __launch_bounds__(256) void k_gemm(
    const ushort_t* __restrict__ A, int lda,
    const ushort_t* __restrict__ B, int ldb,
    void* __restrict__ Cp, int ldc,
    const float* __restrict__ bias,
    int ksteps, int ntiles, int nlim, int bf16out)
{
    __shared__ __align__(16) ushort_t As[64 * 32];
    __shared__ __align__(16) ushort_t Bs[64 * 32];
    const int tid  = threadIdx.x;
    const int lane = tid & 63, wave = tid >> 6;
    const int wm = wave >> 1, wn = wave & 1;
    const int m0 = ((int)blockIdx.x / ntiles) * 64;
    const int n0 = ((int)blockIdx.x % ntiles) * 64;

    const int srow = tid >> 2;
    const int cs   = tid & 3;
    const int cl   = cs ^ ((srow >> 1) & 3);
    const ushort_t* gA = A + (size_t)(m0 + srow) * lda + cl * 8;
    const ushort_t* gB = B + (size_t)(n0 + srow) * ldb + cl * 8;
    ushort_t* lA = &As[tid * 8];
    ushort_t* lB = &Bs[tid * 8];

    const int q  = lane >> 4;
    const int fr = lane & 15;
    int aoff[2], boff[2];
#pragma unroll
    for (int s = 0; s < 2; ++s) {
        const int ra = wm * 32 + s * 16 + fr;
        aoff[s] = (ra * 4 + (q ^ ((ra >> 1) & 3))) * 8;
        const int rb = wn * 32 + s * 16 + fr;
        boff[s] = (rb * 4 + (q ^ ((rb >> 1) & 3))) * 8;
    }

    f32x4 acc[2][2] = {};
    for (int ks = 0; ks < ksteps; ++ks) {
        const int k0 = ks * 32;
        async_copy16(gA + k0, lA);
        async_copy16(gB + k0, lB);
        __syncthreads();
        short8 a[2], b[2];
#pragma unroll
        for (int s = 0; s < 2; ++s) {
            a[s] = *(const short8*)&As[aoff[s]];
            b[s] = *(const short8*)&Bs[boff[s]];
        }
#pragma unroll
        for (int ms = 0; ms < 2; ++ms)
#pragma unroll
            for (int ns = 0; ns < 2; ++ns)
                acc[ms][ns] = __builtin_amdgcn_mfma_f32_16x16x32_bf16(
                    a[ms], b[ns], acc[ms][ns], 0, 0, 0);
        __syncthreads();
    }

#pragma unroll
    for (int ms = 0; ms < 2; ++ms)
#pragma unroll
        for (int ns = 0; ns < 2; ++ns) {
            const int n_abs = n0 + wn * 32 + ns * 16 + fr;
            if (n_abs >= nlim) continue;
            const float bv = bias ? bias[n_abs] : 0.f;
#pragma unroll
            for (int reg = 0; reg < 4; ++reg) {
                const int m_abs = m0 + wm * 32 + ms * 16 + q * 4 + reg;
                const float v = acc[ms][ns][reg] + bv;
                if (bf16out) ((ushort_t*)Cp)[(size_t)m_abs * ldc + n_abs] = f2bf(v);
                else         ((float*)Cp)[(size_t)m_abs * ldc + n_abs] = v;
            }
        }
}

// LN(relu(Epre + enc_b)) -> Abuf cols [0,250). One wave per row, us4 loads.
__global__ __launch_bounds__(256) void k_lnenc(const ushort_t* __restrict__ Epre,
    const float* __restrict__ eb, const float* __restrict__ eg,
    const float* __restrict__ ebt, ushort_t* __restrict__ Abuf)
{
    const int wave = threadIdx.x >> 6, lane = threadIdx.x & 63;
    const int row = blockIdx.x * 4 + wave;
    const int c0 = 4 * lane;

    const us4 v = *(const us4*)&Epre[(size_t)row * 256 + c0];
    float y[4]; float sm = 0.f, sq = 0.f;
#pragma unroll
    for (int t = 0; t < 4; ++t) {
        const int cc = c0 + t;
        float z = 0.f;
        if (cc < H) z = fmaxf(bf2f(v[t]) + eb[cc], 0.f);
        y[t] = z; sm += z; sq += z * z;
    }
    wave_reduce2(sm, sq);
    const float mu = sm * (1.f / H);
    const float rs = rsqrtf(sq * (1.f / H) - mu * mu + EPS);
    ushort_t o[4];
#pragma unroll
    for (int t = 0; t < 4; ++t) {
        const int cc = c0 + t;
        o[t] = (cc < H) ? f2bf((y[t] - mu) * rs * eg[cc] + ebt[cc]) : (ushort_t)0;
    }
    ushort_t* dst = Abuf + (size_t)row * KP + c0;
    if (c0 + 3 < H) { *(us4*)dst = (us4){o[0], o[1], o[2], o[3]}; }
    else {
        if (c0 + 1 < H) *(us2*)dst = (us2){o[0], o[1]};
    }
}

// Co[r][0:256] = LN(relu(P_g + Q_qr + core_b)) bf16, pad cols = 0.
// One wave per GROUP: P loaded once, 7 partner rows.
__global__ __launch_bounds__(256) void k_core(const ushort_t* __restrict__ PQb,
    const float* __restrict__ core_b, const float* __restrict__ core_g,
    const float* __restrict__ core_bt, ushort_t* __restrict__ Co)
{
    const int wave = threadIdx.x >> 6, lane = threadIdx.x & 63;
    const int g = blockIdx.x * 4 + wave;        // group 0..16383
    const int i = g & 7;
    const int c = lane * 4;

    const us4 pu = *(const us4*)&PQb[(size_t)g * PQS + c];
    float pe[4], cb[4], cg[4], cbt[4]; bool vl[4];
#pragma unroll
    for (int t = 0; t < 4; ++t) {
        vl[t]  = (c + t) < H;
        pe[t]  = bf2f(pu[t]);
        cb[t]  = vl[t] ? core_b[c + t]  : 0.f;
        cg[t]  = vl[t] ? core_g[c + t]  : 0.f;
        cbt[t] = vl[t] ? core_bt[c + t] : 0.f;
    }
#pragma unroll 1
    for (int jj = 0; jj < 7; ++jj) {
        const int j = jj + (jj >= i ? 1 : 0);
        const int qr = (g & ~7) + j;
        const us4 qu = *(const us4*)&PQb[(size_t)qr * PQS + 256 + c];
        float z[4]; float sm = 0.f, sq = 0.f;
#pragma unroll
        for (int t = 0; t < 4; ++t) {
            z[t] = vl[t] ? fmaxf(pe[t] + bf2f(qu[t]) + cb[t], 0.f) : 0.f;
            sm += z[t]; sq += z[t] * z[t];
        }
        wave_reduce2(sm, sq);
        const float mu = sm * (1.f / H);
        const float rs = rsqrtf(sq * (1.f / H) - mu * mu + EPS);
        us4 o;
#pragma unroll
        for (int t = 0; t < 4; ++t)
            o[t] = vl[t] ? f2bf((z[t] - mu) * rs * cg[t] + cbt[t]) : (ushort_t)0;
        *(us4*)&Co[((size_t)g * 7 + jj) * 256 + c] = o;
    }
}

// Cs[r][0:352] = Co_r @ [ctxW|attW1]^T (bf16 out). Pure async-staged GEMM:
// M=64/block, N=384 resident. 512 thr = 8 waves (2x4); acc[2][6] = 48 AGPR/wave.
__global__ __launch_bounds__(512, 4) void k_cs(
    const ushort_t* __restrict__ Co,
    const ushort_t* __restrict__ Wca,   // [384][256] bf16
    ushort_t* __restrict__ Cs)
{
    __shared__ __align__(16) ushort_t As[64 * 32];    // 4096 B
    __shared__ __align__(16) ushort_t Bs[384 * 32];   // 24576 B
    const int tid = threadIdx.x, lane = tid & 63, wave = tid >> 6;
    const int wm = wave >> 2, wn = wave & 3;
    const int R0 = (int)blockIdx.x * 64;

    // A-staging (threads 0..255): thread -> (row ar, chunk acb), XOR swizzle
    const int ar = tid >> 2, acb = tid & 3;
    const bool aon = tid < 256;
    const int acl = acb ^ ((ar >> 1) & 3);
    const ushort_t* gA = Co + (size_t)(R0 + ar) * 256 + acl * 8;

    const int q = lane >> 4, fr = lane & 15;

    f32x4 acc[2][6] = {};
    for (int ks = 0; ks < 8; ++ks) {
        const int k0 = ks * 32;
        if (aon) async_copy16(gA + k0, &As[tid * 8]);
#pragma unroll
        for (int it = 0; it < 3; ++it) {
            const int ci  = it * 512 + tid;
            const int rb  = ci >> 2, cb2 = ci & 3;
            const int clb = cb2 ^ ((rb >> 1) & 3);
            async_copy16(Wca + (size_t)rb * 256 + k0 + clb * 8, &Bs[ci * 8]);
        }
        __syncthreads();
        short8 a[2];
#pragma unroll
        for (int ms = 0; ms < 2; ++ms) {
            const int row = wm * 32 + ms * 16 + fr;
            a[ms] = *(const short8*)&As[(row * 4 + (q ^ ((row >> 1) & 3))) * 8];
        }
#pragma unroll
        for (int nt = 0; nt < 6; ++nt) {
            const int n = wn * 96 + nt * 16 + fr;
            const short8 b = *(const short8*)&Bs[(n * 4 + (q ^ ((n >> 1) & 3))) * 8];
#pragma unroll
            for (int ms = 0; ms < 2; ++ms)
                acc[ms][nt] = __builtin_amdgcn_mfma_f32_16x16x32_bf16(
                    a[ms], b, acc[ms][nt], 0, 0, 0);
        }
        __syncthreads();
    }

#pragma unroll
    for (int ms = 0; ms < 2; ++ms)
#pragma unroll
        for (int nt = 0; nt < 6; ++nt) {
            const int col = wn * 96 + nt * 16 + fr;
            if (col >= CSLD) continue;
#pragma unroll
            for (int reg = 0; reg < 4; ++reg) {
                const int row = R0 + wm * 32 + ms * 16 + q * 4 + reg;
                Cs[(size_t)row * CSLD + col] = f2bf(acc[ms][nt][reg]);
            }
        }
}

// eff[g] = sum_j sigmoid(att(row)) * LN_ctx(row). One wave per group, vector loads.
__global__ __launch_bounds__(256) void k_eff(const ushort_t* __restrict__ Cs,
    const float* __restrict__ ctx_b, const float* __restrict__ ctx_g, const float* __restrict__ ctx_bt,
    const float* __restrict__ att_b1, const float* __restrict__ att_g, const float* __restrict__ att_bt,
    const float* __restrict__ attW2, const float* __restrict__ att_b2,
    ushort_t* __restrict__ Abuf)
{
    const int wave = threadIdx.x >> 6, lane = threadIdx.x & 63;
    const int g = blockIdx.x * 4 + wave;
    const int c0 = 4 * lane;           // 0..252
    const int c1 = 256 + 2 * lane;     // 256..382, valid while c1+1 < CSLD (lane<48)
    const bool l48 = lane < 48;

    int ce[6]; bool eC[6], eA[6]; float b_[6], g_[6], bt_[6], w2_[6];
#pragma unroll
    for (int e = 0; e < 6; ++e) {
        ce[e] = (e < 4) ? (c0 + e) : (c1 + (e - 4));
        const bool vld = (e < 4) || l48;
        eC[e] = vld && (ce[e] < H);
        eA[e] = vld && (ce[e] >= H) && (ce[e] < H + HA);
        if (eC[e])      { b_[e] = ctx_b[ce[e]]; g_[e] = ctx_g[ce[e]]; bt_[e] = ctx_bt[ce[e]]; w2_[e] = 0.f; }
        else if (eA[e]) { const int ca = ce[e] - H;
                          b_[e] = att_b1[ca]; g_[e] = att_g[ca]; bt_[e] = att_bt[ca]; w2_[e] = attW2[ca]; }
        else            { b_[e] = g_[e] = bt_[e] = w2_[e] = 0.f; }
    }
    const float ab2 = att_b2[0];
    float effa[4] = {0.f, 0.f, 0.f, 0.f};

#pragma unroll 1
    for (int jj = 0; jj < 7; ++jj) {
        const size_t base = ((size_t)g * 7 + jj) * CSLD;
        const us4 v0 = *(const us4*)&Cs[base + c0];
        us2 v1 = {0, 0};
        if (l48) v1 = *(const us2*)&Cs[base + c1];
        float raw[6];
#pragma unroll
        for (int e = 0; e < 4; ++e) raw[e] = bf2f(v0[e]);
        raw[4] = bf2f(v1[0]); raw[5] = bf2f(v1[1]);

        float sv[6]; float smc = 0.f, sqc = 0.f, sma = 0.f, sqa = 0.f;
#pragma unroll
        for (int e = 0; e < 6; ++e) {
            if (eC[e]) {
                const float z = fmaxf(raw[e] + b_[e], 0.f);
                sv[e] = z; smc += z; sqc += z * z;
            } else if (eA[e]) {
                const float za = tanhf(raw[e] + b_[e]);
                sv[e] = za; sma += za; sqa += za * za;
            } else sv[e] = 0.f;
        }
        wave_reduce2(smc, sqc);
        wave_reduce2(sma, sqa);
        const float muC = smc * (1.f / H);
        const float rsC = rsqrtf(sqc * (1.f / H) - muC * muC + EPS);
        const float muA = sma * (1.f / HA);
        const float rsA = rsqrtf(sqa * (1.f / HA) - muA * muA + EPS);
        float dot = 0.f;
#pragma unroll
        for (int e = 0; e < 6; ++e) {
            if (eA[e]) {
                const float ath = (sv[e] - muA) * rsA * g_[e] + bt_[e];
                dot += ath * w2_[e];
            }
        }
        dot = wave_reduce1(dot);
        const float ag = 1.f / (1.f + expf(-(dot + ab2)));
#pragma unroll
        for (int e = 0; e < 4; ++e) {
            if (eC[e]) {
                const float ctxo = (sv[e] - muC) * rsC * g_[e] + bt_[e];
                effa[e] = fmaf(ag, ctxo, effa[e]);
            }
        }
    }
    ushort_t* dst = Abuf + (size_t)g * KP + H + c0;
    if (c0 + 1 < H) *(us2*)dst       = (us2){f2bf(effa[0]), f2bf(effa[1])};
    if (c0 + 3 < H) *(us2*)(dst + 2) = (us2){f2bf(effa[2]), f2bf(effa[3])};
}

extern "C" void kernel_launch(void* const* d_in, const int* in_sizes, int n_in,
                              void* d_out, int out_size, void* d_ws, size_t ws_size,
                              hipStream_t stream)
{
    const float* x      = (const float*)d_in[0];
    const float* state  = (const float*)d_in[1];
    const float* enc_W  = (const float*)d_in[2];
    const float* enc_b  = (const float*)d_in[3];
    const float* enc_g  = (const float*)d_in[4];
    const float* enc_bt = (const float*)d_in[5];
    const float* core_W = (const float*)d_in[6];
    const float* core_b = (const float*)d_in[7];
    const float* core_g = (const float*)d_in[8];
    const float* core_bt= (const float*)d_in[9];
    const float* ctx_W  = (const float*)d_in[10];
    const float* ctx_b  = (const float*)d_in[11];
    const float* ctx_g  = (const float*)d_in[12];
    const float* ctx_bt = (const float*)d_in[13];
    const float* att_W1 = (const float*)d_in[14];
    const float* att_b1 = (const float*)d_in[15];
    const float* att_g  = (const float*)d_in[16];
    const float* att_bt = (const float*)d_in[17];
    const float* att_W2 = (const float*)d_in[18];
    const float* att_b2 = (const float*)d_in[19];
    const float* out_W  = (const float*)d_in[20];
    const float* out_b  = (const float*)d_in[21];
    float* out = (float*)d_out;

    // layout (ushort units); Sb/Epre/PQb alias the Cs region (dead before k_cs)
    ushort_t* Abuf = (ushort_t*)d_ws;                   // 16384*1088      (35.7 MB)
    ushort_t* Wt   = Abuf + (size_t)ROWS * KP;          // 256*1088
    ushort_t* Wpq  = Wt + (size_t)256 * KP;             // 512*256
    ushort_t* Wca  = Wpq + (size_t)512 * 256;           // 384*256
    ushort_t* Wenc = Wca + (size_t)384 * 256;           // 256*256
    ushort_t* Co   = Wenc + (size_t)256 * 256;          // 114688*256     (58.7 MB)
    ushort_t* Cs   = Co + (size_t)PROWS * 256;          // 114688*352     (80.7 MB)
    ushort_t* Sb   = Cs;                                // 16384*256  (aliased)
    ushort_t* Epre = Sb + (size_t)ROWS * 256;           // 16384*256  (aliased)
    ushort_t* PQb  = Epre + (size_t)ROWS * 256;         // 16384*512  (aliased)

    k_prep  <<<2432 + ROWS, 256, 0, stream>>>(out_W, core_W, ctx_W, att_W1, enc_W,
                                              state, x, Wt, Wpq, Wca, Wenc, Sb, Abuf);
    // Epre = state @ enc_W  (bf16 MFMA)
    k_gemm  <<<(ROWS / 64) * 4, 256, 0, stream>>>(Sb, 256, Wenc, 256, Epre, 256,
                                                  nullptr, 8, 4, 256, 1);
    k_lnenc <<<ROWS / 4, 256, 0, stream>>>(Epre, enc_b, enc_g, enc_bt, Abuf);
    // PQb = s1 @ [W_top | W_bot]  (bf16 MFMA, bf16 out)
    k_gemm  <<<(ROWS / 64) * 8, 256, 0, stream>>>(Abuf, KP, Wpq, 256, PQb, PQS,
                                                  nullptr, 8, 8, 512, 1);
    k_core  <<<ROWS / 4, 256, 0, stream>>>(PQb, core_b, core_g, core_bt, Co);
    k_cs    <<<PROWS / 64, 512, 0, stream>>>(Co, Wca, Cs);
    k_eff   <<<ROWS / 4, 256, 0, stream>>>(Cs, ctx_b, ctx_g, ctx_bt,
                                           att_b1, att_g, att_bt, att_W2, att_b2,
                                           Abuf);
    // out = [s1 | eff | x] @ out_W + b  (bf16 MFMA, fp32 out)
    k_gemm  <<<(ROWS / 64) * 4, 256, 0, stream>>>(Abuf, KP, Wt, KP, out, H,
                                                  out_b, KP / 32, 4, H, 0);
}

// Round 9
// 336.966 us; speedup vs baseline: 1.8158x; 1.0433x over previous
//
#include <hip/hip_runtime.h>
#include <math.h>

#define KK 8
#define H 250          // SIZE == h1
#define MDIM 576
#define NB 2048
#define HA 100
#define ROWS (NB*KK)   // 16384
#define PROWS (ROWS*7) // 114688 pair rows
#define PQS 512        // PQb row stride (ushort): P at 0..249, Q at 256..505
#define KP 1088        // padded K for out GEMM (1076 -> 34*32)
#define CSLD 352       // Cs row stride (ushort): 250 ctx + 100 att + 2 pad
#define EPS 1e-5f

typedef unsigned short ushort_t;
typedef short short8 __attribute__((ext_vector_type(8)));
typedef unsigned short us8 __attribute__((ext_vector_type(8)));
typedef unsigned short us4 __attribute__((ext_vector_type(4)));
typedef unsigned short us2 __attribute__((ext_vector_type(2)));
typedef float f32x4 __attribute__((ext_vector_type(4)));

__device__ __forceinline__ void wave_reduce2(float& a, float& b) {
#pragma unroll
    for (int m = 1; m < 64; m <<= 1) {
        a += __shfl_xor(a, m, 64);
        b += __shfl_xor(b, m, 64);
    }
}
__device__ __forceinline__ void wave_reduce3(float& a, float& b, float& c) {
#pragma unroll
    for (int m = 1; m < 64; m <<= 1) {
        a += __shfl_xor(a, m, 64);
        b += __shfl_xor(b, m, 64);
        c += __shfl_xor(c, m, 64);
    }
}
__device__ __forceinline__ float wave_reduce1(float a) {
#pragma unroll
    for (int m = 1; m < 64; m <<= 1) a += __shfl_xor(a, m, 64);
    return a;
}

__device__ __forceinline__ void async_copy16(const void* g, void* l) {
    __builtin_amdgcn_global_load_lds(
        (const __attribute__((address_space(1))) void*)g,
        (__attribute__((address_space(3))) void*)l, 16, 0, 0);
}

__device__ __forceinline__ ushort_t f2bf(float v) {
    union { float f; unsigned int u; } c; c.f = v;
    unsigned int x = c.u;
    x += 0x7fff + ((x >> 16) & 1);   // RNE
    return (ushort_t)(x >> 16);
}
__device__ __forceinline__ float bf2f(ushort_t v) {
    union { unsigned int u; float f; } c; c.u = ((unsigned int)v) << 16;
    return c.f;
}
// fast tanh: 1 - 2/(exp(2x)+1)  (v_exp + v_rcp; ~1e-6 rel err, << bf16 ulp)
__device__ __forceinline__ float ftanh(float x) {
    const float e = __expf(2.f * x);
    return 1.f - 2.f * __builtin_amdgcn_rcpf(e + 1.f);
}
__device__ __forceinline__ float fsigmoid(float x) {
    return __builtin_amdgcn_rcpf(1.f + __expf(-x));
}

// ---- fused prep: Wt | Wpq | Wca | Wenc | Sb | x->Abuf ----
__global__ __launch_bounds__(256) void k_prep(
    const float* __restrict__ out_W, const float* __restrict__ core_W,
    const float* __restrict__ ctx_W, const float* __restrict__ att_W1,
    const float* __restrict__ enc_W, const float* __restrict__ state,
    const float* __restrict__ x,
    ushort_t* __restrict__ Wt, ushort_t* __restrict__ Wpq,
    ushort_t* __restrict__ Wca, ushort_t* __restrict__ Wenc,
    ushort_t* __restrict__ Sb, ushort_t* __restrict__ Abuf)
{
    const int b = blockIdx.x, t = threadIdx.x;
    if (b < 256) {                      // Wt[n][k] = out_W[k][n]
        const int n = b;
        for (int k = t; k < KP; k += 256) {
            const float v = (n < H && k < 1076) ? out_W[(size_t)k * H + n] : 0.f;
            Wt[(size_t)n * KP + k] = f2bf(v);
        }
    } else if (b < 768) {               // Wpq
        const int n = b - 256, k = t;
        float v = 0.f;
        if (k < H) {
            if (n < H)                    v = core_W[(size_t)k * H + n];
            else if (n >= 256 && n < 506) v = core_W[(size_t)(H + k) * H + (n - 256)];
        }
        Wpq[(size_t)n * 256 + k] = f2bf(v);
    } else if (b < 1152) {              // Wca
        const int n = b - 768, k = t;
        float v = 0.f;
        if (k < H) {
            if (n < H)           v = ctx_W[(size_t)k * H + n];
            else if (n < H + HA) v = att_W1[(size_t)k * HA + (n - H)];
        }
        Wca[(size_t)n * 256 + k] = f2bf(v);
    } else if (b < 1408) {              // Wenc[n][k] = enc_W[k][n]
        const int n = b - 1152, k = t;
        const float v = (n < H && k < H) ? enc_W[(size_t)k * H + n] : 0.f;
        Wenc[(size_t)n * 256 + k] = f2bf(v);
    } else if (b < 2432) {              // Sb: state padded to 256, bf16
        const int r0 = (b - 1408) * 16;
        for (int idx = t; idx < 16 * 256; idx += 256) {
            const int r = r0 + (idx >> 8), k = idx & 255;
            const float v = (k < H) ? state[(size_t)r * H + k] : 0.f;
            Sb[(size_t)r * 256 + k] = f2bf(v);
        }
    } else {                            // Abuf cols [500,1088): x + pad
        const int row = b - 2432;
        for (int c = 500 + t; c < KP; c += 256) {
            const float v = (c < 500 + MDIM) ? x[(size_t)row * MDIM + (c - 500)] : 0.f;
            Abuf[(size_t)row * KP + c] = f2bf(v);
        }
    }
}

// generic bf16 MFMA GEMM: C[m][n] = sum_k A[m][k]*B[n][k] (+bias[n]); f32/bf16 out
__global__ __launch_bounds__(256) void k_gemm(
    const ushort_t* __restrict__ A, int lda,
    const ushort_t* __restrict__ B, int ldb,
    void* __restrict__ Cp, int ldc,
    const float* __restrict__ bias,
    int ksteps, int ntiles, int nlim, int bf16out)
{
    __shared__ __align__(16) ushort_t As[64 * 32];
    __shared__ __align__(16) ushort_t Bs[64 * 32];
    const int tid  = threadIdx.x;
    const int lane = tid & 63, wave = tid >> 6;
    const int wm = wave >> 1, wn = wave & 1;
    const int m0 = ((int)blockIdx.x / ntiles) * 64;
    const int n0 = ((int)blockIdx.x % ntiles) * 64;

    const int srow = tid >> 2;
    const int cs   = tid & 3;
    const int cl   = cs ^ ((srow >> 1) & 3);
    const ushort_t* gA = A + (size_t)(m0 + srow) * lda + cl * 8;
    const ushort_t* gB = B + (size_t)(n0 + srow) * ldb + cl * 8;
    ushort_t* lA = &As[tid * 8];
    ushort_t* lB = &Bs[tid * 8];

    const int q  = lane >> 4;
    const int fr = lane & 15;
    int aoff[2], boff[2];
#pragma unroll
    for (int s = 0; s < 2; ++s) {
        const int ra = wm * 32 + s * 16 + fr;
        aoff[s] = (ra * 4 + (q ^ ((ra >> 1) & 3))) * 8;
        const int rb = wn * 32 + s * 16 + fr;
        boff[s] = (rb * 4 + (q ^ ((rb >> 1) & 3))) * 8;
    }

    f32x4 acc[2][2] = {};
    for (int ks = 0; ks < ksteps; ++ks) {
        const int k0 = ks * 32;
        async_copy16(gA + k0, lA);
        async_copy16(gB + k0, lB);
        __syncthreads();
        short8 a[2], b[2];
#pragma unroll
        for (int s = 0; s < 2; ++s) {
            a[s] = *(const short8*)&As[aoff[s]];
            b[s] = *(const short8*)&Bs[boff[s]];
        }
#pragma unroll
        for (int ms = 0; ms < 2; ++ms)
#pragma unroll
            for (int ns = 0; ns < 2; ++ns)
                acc[ms][ns] = __builtin_amdgcn_mfma_f32_16x16x32_bf16(
                    a[ms], b[ns], acc[ms][ns], 0, 0, 0);
        __syncthreads();
    }

#pragma unroll
    for (int ms = 0; ms < 2; ++ms)
#pragma unroll
        for (int ns = 0; ns < 2; ++ns) {
            const int n_abs = n0 + wn * 32 + ns * 16 + fr;
            if (n_abs >= nlim) continue;
            const float bv = bias ? bias[n_abs] : 0.f;
#pragma unroll
            for (int reg = 0; reg < 4; ++reg) {
                const int m_abs = m0 + wm * 32 + ms * 16 + q * 4 + reg;
                const float v = acc[ms][ns][reg] + bv;
                if (bf16out) ((ushort_t*)Cp)[(size_t)m_abs * ldc + n_abs] = f2bf(v);
                else         ((float*)Cp)[(size_t)m_abs * ldc + n_abs] = v;
            }
        }
}

// LN(relu(Epre + enc_b)) -> Abuf cols [0,250). One wave per row, us4 loads.
__global__ __launch_bounds__(256) void k_lnenc(const ushort_t* __restrict__ Epre,
    const float* __restrict__ eb, const float* __restrict__ eg,
    const float* __restrict__ ebt, ushort_t* __restrict__ Abuf)
{
    const int wave = threadIdx.x >> 6, lane = threadIdx.x & 63;
    const int row = blockIdx.x * 4 + wave;
    const int c0 = 4 * lane;

    const us4 v = *(const us4*)&Epre[(size_t)row * 256 + c0];
    float y[4]; float sm = 0.f, sq = 0.f;
#pragma unroll
    for (int t = 0; t < 4; ++t) {
        const int cc = c0 + t;
        float z = 0.f;
        if (cc < H) z = fmaxf(bf2f(v[t]) + eb[cc], 0.f);
        y[t] = z; sm += z; sq += z * z;
    }
    wave_reduce2(sm, sq);
    const float mu = sm * (1.f / H);
    const float rs = __builtin_amdgcn_rsqf(sq * (1.f / H) - mu * mu + EPS);
    ushort_t o[4];
#pragma unroll
    for (int t = 0; t < 4; ++t) {
        const int cc = c0 + t;
        o[t] = (cc < H) ? f2bf((y[t] - mu) * rs * eg[cc] + ebt[cc]) : (ushort_t)0;
    }
    ushort_t* dst = Abuf + (size_t)row * KP + c0;
    if (c0 + 3 < H) { *(us4*)dst = (us4){o[0], o[1], o[2], o[3]}; }
    else {
        if (c0 + 1 < H) *(us2*)dst = (us2){o[0], o[1]};
    }
}

// Co[r][0:256] = LN(relu(P_g + Q_qr + core_b)) bf16, pad cols = 0.
// One wave per GROUP: P loaded once, 7 partner rows.
__global__ __launch_bounds__(256) void k_core(const ushort_t* __restrict__ PQb,
    const float* __restrict__ core_b, const float* __restrict__ core_g,
    const float* __restrict__ core_bt, ushort_t* __restrict__ Co)
{
    const int wave = threadIdx.x >> 6, lane = threadIdx.x & 63;
    const int g = blockIdx.x * 4 + wave;        // group 0..16383
    const int i = g & 7;
    const int c = lane * 4;

    const us4 pu = *(const us4*)&PQb[(size_t)g * PQS + c];
    float pe[4], cb[4], cg[4], cbt[4]; bool vl[4];
#pragma unroll
    for (int t = 0; t < 4; ++t) {
        vl[t]  = (c + t) < H;
        pe[t]  = bf2f(pu[t]);
        cb[t]  = vl[t] ? core_b[c + t]  : 0.f;
        cg[t]  = vl[t] ? core_g[c + t]  : 0.f;
        cbt[t] = vl[t] ? core_bt[c + t] : 0.f;
    }
#pragma unroll 1
    for (int jj = 0; jj < 7; ++jj) {
        const int j = jj + (jj >= i ? 1 : 0);
        const int qr = (g & ~7) + j;
        const us4 qu = *(const us4*)&PQb[(size_t)qr * PQS + 256 + c];
        float z[4]; float sm = 0.f, sq = 0.f;
#pragma unroll
        for (int t = 0; t < 4; ++t) {
            z[t] = vl[t] ? fmaxf(pe[t] + bf2f(qu[t]) + cb[t], 0.f) : 0.f;
            sm += z[t]; sq += z[t] * z[t];
        }
        wave_reduce2(sm, sq);
        const float mu = sm * (1.f / H);
        const float rs = __builtin_amdgcn_rsqf(sq * (1.f / H) - mu * mu + EPS);
        us4 o;
#pragma unroll
        for (int t = 0; t < 4; ++t)
            o[t] = vl[t] ? f2bf((z[t] - mu) * rs * cg[t] + cbt[t]) : (ushort_t)0;
        *(us4*)&Co[((size_t)g * 7 + jj) * 256 + c] = o;
    }
}

// Cs[r][0:352] = Co_r @ [ctxW|attW1]^T (bf16 out). Pure async-staged GEMM:
// M=64/block, N=384 resident. 512 thr = 8 waves (2x4); acc[2][6] = 48 AGPR/wave.
__global__ __launch_bounds__(512, 4) void k_cs(
    const ushort_t* __restrict__ Co,
    const ushort_t* __restrict__ Wca,   // [384][256] bf16
    ushort_t* __restrict__ Cs)
{
    __shared__ __align__(16) ushort_t As[64 * 32];    // 4096 B
    __shared__ __align__(16) ushort_t Bs[384 * 32];   // 24576 B
    const int tid = threadIdx.x, lane = tid & 63, wave = tid >> 6;
    const int wm = wave >> 2, wn = wave & 3;
    const int R0 = (int)blockIdx.x * 64;

    const int ar = tid >> 2, acb = tid & 3;
    const bool aon = tid < 256;
    const int acl = acb ^ ((ar >> 1) & 3);
    const ushort_t* gA = Co + (size_t)(R0 + ar) * 256 + acl * 8;

    const int q = lane >> 4, fr = lane & 15;

    f32x4 acc[2][6] = {};
    for (int ks = 0; ks < 8; ++ks) {
        const int k0 = ks * 32;
        if (aon) async_copy16(gA + k0, &As[tid * 8]);
#pragma unroll
        for (int it = 0; it < 3; ++it) {
            const int ci  = it * 512 + tid;
            const int rb  = ci >> 2, cb2 = ci & 3;
            const int clb = cb2 ^ ((rb >> 1) & 3);
            async_copy16(Wca + (size_t)rb * 256 + k0 + clb * 8, &Bs[ci * 8]);
        }
        __syncthreads();
        short8 a[2];
#pragma unroll
        for (int ms = 0; ms < 2; ++ms) {
            const int row = wm * 32 + ms * 16 + fr;
            a[ms] = *(const short8*)&As[(row * 4 + (q ^ ((row >> 1) & 3))) * 8];
        }
#pragma unroll
        for (int nt = 0; nt < 6; ++nt) {
            const int n = wn * 96 + nt * 16 + fr;
            const short8 b = *(const short8*)&Bs[(n * 4 + (q ^ ((n >> 1) & 3))) * 8];
#pragma unroll
            for (int ms = 0; ms < 2; ++ms)
                acc[ms][nt] = __builtin_amdgcn_mfma_f32_16x16x32_bf16(
                    a[ms], b, acc[ms][nt], 0, 0, 0);
        }
        __syncthreads();
    }

#pragma unroll
    for (int ms = 0; ms < 2; ++ms)
#pragma unroll
        for (int nt = 0; nt < 6; ++nt) {
            const int col = wn * 96 + nt * 16 + fr;
            if (col >= CSLD) continue;
#pragma unroll
            for (int reg = 0; reg < 4; ++reg) {
                const int row = R0 + wm * 32 + ms * 16 + q * 4 + reg;
                Cs[(size_t)row * CSLD + col] = f2bf(acc[ms][nt][reg]);
            }
        }
}

// eff[g] = sum_j sigmoid(att(row)) * LN_ctx(row). One wave per group.
// Factored epilogue: effa_e = gamma_e*(A_e - S1) + beta_e*S0, A_e += (ag*rs)*z_e.
// Attention dot factored so only ONE reduction pass (3 values) per row.
__global__ __launch_bounds__(256) void k_eff(const ushort_t* __restrict__ Cs,
    const float* __restrict__ ctx_b, const float* __restrict__ ctx_g, const float* __restrict__ ctx_bt,
    const float* __restrict__ att_b1, const float* __restrict__ att_g, const float* __restrict__ att_bt,
    const float* __restrict__ attW2, const float* __restrict__ att_b2,
    ushort_t* __restrict__ Abuf)
{
    const int wave = threadIdx.x >> 6, lane = threadIdx.x & 63;
    const int g = blockIdx.x * 4 + wave;
    const int c0 = 4 * lane;           // 0..252
    const int c1 = 256 + 2 * lane;     // 256..382, valid while lane<48
    const bool l48 = lane < 48;

    int ce[6]; bool eC[6], eA[6]; float b_[6], g_[6], bt_[6], w2_[6];
#pragma unroll
    for (int e = 0; e < 6; ++e) {
        ce[e] = (e < 4) ? (c0 + e) : (c1 + (e - 4));
        const bool vld = (e < 4) || l48;
        eC[e] = vld && (ce[e] < H);
        eA[e] = vld && (ce[e] >= H) && (ce[e] < H + HA);
        if (eC[e])      { b_[e] = ctx_b[ce[e]]; g_[e] = ctx_g[ce[e]]; bt_[e] = ctx_bt[ce[e]]; w2_[e] = 0.f; }
        else if (eA[e]) { const int ca = ce[e] - H;
                          b_[e] = att_b1[ca]; g_[e] = att_g[ca]; bt_[e] = att_bt[ca]; w2_[e] = attW2[ca]; }
        else            { b_[e] = g_[e] = bt_[e] = w2_[e] = 0.f; }
    }
    // row-invariant attention sums: Sgw = sum(gamma_a*w2), Sbw = sum(beta_a*w2)
    float sgw = 0.f, sbw = 0.f;
#pragma unroll
    for (int e = 0; e < 6; ++e) if (eA[e]) {
        sgw += g_[e] * w2_[e];
        sbw += bt_[e] * w2_[e];
    }
    wave_reduce2(sgw, sbw);
    const float ab2 = att_b2[0] + sbw;

    float A4[4] = {0.f, 0.f, 0.f, 0.f};   // per-elem z accumulator
    float S0 = 0.f, S1 = 0.f;             // sum(ag), sum(ag*rsC*muC)

#pragma unroll 1
    for (int jj = 0; jj < 7; ++jj) {
        const size_t base = ((size_t)g * 7 + jj) * CSLD;
        const us4 v0 = *(const us4*)&Cs[base + c0];
        us2 v1 = {0, 0};
        if (l48) v1 = *(const us2*)&Cs[base + c1];
        float raw[6];
#pragma unroll
        for (int e = 0; e < 4; ++e) raw[e] = bf2f(v0[e]);
        raw[4] = bf2f(v1[0]); raw[5] = bf2f(v1[1]);

        float z[4];
        float smc = 0.f, sqc = 0.f, sma = 0.f, sqa = 0.f, szgw = 0.f;
#pragma unroll
        for (int e = 0; e < 6; ++e) {
            if (eC[e]) {
                const float zz = fmaxf(raw[e] + b_[e], 0.f);
                z[e] = zz; smc += zz; sqc = fmaf(zz, zz, sqc);
            } else if (eA[e]) {
                const float za = ftanh(raw[e] + b_[e]);
                sma += za; sqa = fmaf(za, za, sqa);
                szgw = fmaf(za, g_[e] * w2_[e], szgw);
            } else if (e < 4) z[e] = 0.f;
        }
        wave_reduce2(smc, sqc);
        wave_reduce3(sma, sqa, szgw);
        const float muC = smc * (1.f / H);
        const float rsC = __builtin_amdgcn_rsqf(sqc * (1.f / H) - muC * muC + EPS);
        const float muA = sma * (1.f / HA);
        const float rsA = __builtin_amdgcn_rsqf(sqa * (1.f / HA) - muA * muA + EPS);
        const float dot = rsA * (szgw - muA * sgw) + ab2;
        const float ag  = fsigmoid(dot);
        const float cj  = ag * rsC;
        S0 += ag; S1 = fmaf(cj, muC, S1);
#pragma unroll
        for (int e = 0; e < 4; ++e) A4[e] = fmaf(cj, z[e], A4[e]);
    }
    ushort_t o[4];
#pragma unroll
    for (int e = 0; e < 4; ++e)
        o[e] = f2bf(g_[e] * (A4[e] - S1) + bt_[e] * S0);
    ushort_t* dst = Abuf + (size_t)g * KP + H + c0;
    if (c0 + 1 < H) *(us2*)dst       = (us2){o[0], o[1]};
    if (c0 + 3 < H) *(us2*)(dst + 2) = (us2){o[2], o[3]};
}

extern "C" void kernel_launch(void* const* d_in, const int* in_sizes, int n_in,
                              void* d_out, int out_size, void* d_ws, size_t ws_size,
                              hipStream_t stream)
{
    const float* x      = (const float*)d_in[0];
    const float* state  = (const float*)d_in[1];
    const float* enc_W  = (const float*)d_in[2];
    const float* enc_b  = (const float*)d_in[3];
    const float* enc_g  = (const float*)d_in[4];
    const float* enc_bt = (const float*)d_in[5];
    const float* core_W = (const float*)d_in[6];
    const float* core_b = (const float*)d_in[7];
    const float* core_g = (const float*)d_in[8];
    const float* core_bt= (const float*)d_in[9];
    const float* ctx_W  = (const float*)d_in[10];
    const float* ctx_b  = (const float*)d_in[11];
    const float* ctx_g  = (const float*)d_in[12];
    const float* ctx_bt = (const float*)d_in[13];
    const float* att_W1 = (const float*)d_in[14];
    const float* att_b1 = (const float*)d_in[15];
    const float* att_g  = (const float*)d_in[16];
    const float* att_bt = (const float*)d_in[17];
    const float* att_W2 = (const float*)d_in[18];
    const float* att_b2 = (const float*)d_in[19];
    const float* out_W  = (const float*)d_in[20];
    const float* out_b  = (const float*)d_in[21];
    float* out = (float*)d_out;

    // layout (ushort units); Sb/Epre/PQb alias the Cs region (dead before k_cs)
    ushort_t* Abuf = (ushort_t*)d_ws;                   // 16384*1088      (35.7 MB)
    ushort_t* Wt   = Abuf + (size_t)ROWS * KP;          // 256*1088
    ushort_t* Wpq  = Wt + (size_t)256 * KP;             // 512*256
    ushort_t* Wca  = Wpq + (size_t)512 * 256;           // 384*256
    ushort_t* Wenc = Wca + (size_t)384 * 256;           // 256*256
    ushort_t* Co   = Wenc + (size_t)256 * 256;          // 114688*256     (58.7 MB)
    ushort_t* Cs   = Co + (size_t)PROWS * 256;          // 114688*352     (80.7 MB)
    ushort_t* Sb   = Cs;                                // 16384*256  (aliased)
    ushort_t* Epre = Sb + (size_t)ROWS * 256;           // 16384*256  (aliased)
    ushort_t* PQb  = Epre + (size_t)ROWS * 256;         // 16384*512  (aliased)

    k_prep  <<<2432 + ROWS, 256, 0, stream>>>(out_W, core_W, ctx_W, att_W1, enc_W,
                                              state, x, Wt, Wpq, Wca, Wenc, Sb, Abuf);
    // Epre = state @ enc_W  (bf16 MFMA)
    k_gemm  <<<(ROWS / 64) * 4, 256, 0, stream>>>(Sb, 256, Wenc, 256, Epre, 256,
                                                  nullptr, 8, 4, 256, 1);
    k_lnenc <<<ROWS / 4, 256, 0, stream>>>(Epre, enc_b, enc_g, enc_bt, Abuf);
    // PQb = s1 @ [W_top | W_bot]  (bf16 MFMA, bf16 out)
    k_gemm  <<<(ROWS / 64) * 8, 256, 0, stream>>>(Abuf, KP, Wpq, 256, PQb, PQS,
                                                  nullptr, 8, 8, 512, 1);
    k_core  <<<ROWS / 4, 256, 0, stream>>>(PQb, core_b, core_g, core_bt, Co);
    k_cs    <<<PROWS / 64, 512, 0, stream>>>(Co, Wca, Cs);
    k_eff   <<<ROWS / 4, 256, 0, stream>>>(Cs, ctx_b, ctx_g, ctx_bt,
                                           att_b1, att_g, att_bt, att_W2, att_b2,
                                           Abuf);
    // out = [s1 | eff | x] @ out_W + b  (bf16 MFMA, fp32 out)
    k_gemm  <<<(ROWS / 64) * 4, 256, 0, stream>>>(Abuf, KP, Wt, KP, out, H,
                                                  out_b, KP / 32, 4, H, 0);
}

// Round 11
// 333.294 us; speedup vs baseline: 1.8358x; 1.0110x over previous
//
#include <hip/hip_runtime.h>
#include <math.h>

#define KK 8
#define H 250          // SIZE == h1
#define MDIM 576
#define NB 2048
#define HA 100
#define ROWS (NB*KK)   // 16384
#define PROWS (ROWS*7) // 114688 pair rows
#define PQS 512        // PQb row stride (ushort): P at 0..249, Q at 256..505
#define KP 1088        // padded K for out GEMM (1076 -> 34*32)
#define CSLD 352       // Cs row stride (ushort): 250 ctx + 100 att + 2 pad
#define EPS 1e-5f

typedef unsigned short ushort_t;
typedef short short8 __attribute__((ext_vector_type(8)));
typedef unsigned short us8 __attribute__((ext_vector_type(8)));
typedef unsigned short us4 __attribute__((ext_vector_type(4)));
typedef unsigned short us2 __attribute__((ext_vector_type(2)));
typedef float f32x4 __attribute__((ext_vector_type(4)));

__device__ __forceinline__ void wave_reduce2(float& a, float& b) {
#pragma unroll
    for (int m = 1; m < 64; m <<= 1) {
        a += __shfl_xor(a, m, 64);
        b += __shfl_xor(b, m, 64);
    }
}

__device__ __forceinline__ void async_copy16(const void* g, void* l) {
    __builtin_amdgcn_global_load_lds(
        (const __attribute__((address_space(1))) void*)g,
        (__attribute__((address_space(3))) void*)l, 16, 0, 0);
}

__device__ __forceinline__ ushort_t f2bf(float v) {
    union { float f; unsigned int u; } c; c.f = v;
    unsigned int x = c.u;
    x += 0x7fff + ((x >> 16) & 1);   // RNE
    return (ushort_t)(x >> 16);
}
__device__ __forceinline__ float bf2f(ushort_t v) {
    union { unsigned int u; float f; } c; c.u = ((unsigned int)v) << 16;
    return c.f;
}
// fast tanh: 1 - 2/(exp(2x)+1)  (v_exp + v_rcp; ~1e-6 rel err, << bf16 ulp)
__device__ __forceinline__ float ftanh(float x) {
    const float e = __expf(2.f * x);
    return 1.f - 2.f * __builtin_amdgcn_rcpf(e + 1.f);
}
__device__ __forceinline__ float fsigmoid(float x) {
    return __builtin_amdgcn_rcpf(1.f + __expf(-x));
}

// ---- fused prep: Wt | Wpq | Wca | Wenc | Sb | x->Abuf ----
__global__ __launch_bounds__(256) void k_prep(
    const float* __restrict__ out_W, const float* __restrict__ core_W,
    const float* __restrict__ ctx_W, const float* __restrict__ att_W1,
    const float* __restrict__ enc_W, const float* __restrict__ state,
    const float* __restrict__ x,
    ushort_t* __restrict__ Wt, ushort_t* __restrict__ Wpq,
    ushort_t* __restrict__ Wca, ushort_t* __restrict__ Wenc,
    ushort_t* __restrict__ Sb, ushort_t* __restrict__ Abuf)
{
    const int b = blockIdx.x, t = threadIdx.x;
    if (b < 256) {                      // Wt[n][k] = out_W[k][n]
        const int n = b;
        for (int k = t; k < KP; k += 256) {
            const float v = (n < H && k < 1076) ? out_W[(size_t)k * H + n] : 0.f;
            Wt[(size_t)n * KP + k] = f2bf(v);
        }
    } else if (b < 768) {               // Wpq
        const int n = b - 256, k = t;
        float v = 0.f;
        if (k < H) {
            if (n < H)                    v = core_W[(size_t)k * H + n];
            else if (n >= 256 && n < 506) v = core_W[(size_t)(H + k) * H + (n - 256)];
        }
        Wpq[(size_t)n * 256 + k] = f2bf(v);
    } else if (b < 1152) {              // Wca
        const int n = b - 768, k = t;
        float v = 0.f;
        if (k < H) {
            if (n < H)           v = ctx_W[(size_t)k * H + n];
            else if (n < H + HA) v = att_W1[(size_t)k * HA + (n - H)];
        }
        Wca[(size_t)n * 256 + k] = f2bf(v);
    } else if (b < 1408) {              // Wenc[n][k] = enc_W[k][n]
        const int n = b - 1152, k = t;
        const float v = (n < H && k < H) ? enc_W[(size_t)k * H + n] : 0.f;
        Wenc[(size_t)n * 256 + k] = f2bf(v);
    } else if (b < 2432) {              // Sb: state padded to 256, bf16
        const int r0 = (b - 1408) * 16;
        for (int idx = t; idx < 16 * 256; idx += 256) {
            const int r = r0 + (idx >> 8), k = idx & 255;
            const float v = (k < H) ? state[(size_t)r * H + k] : 0.f;
            Sb[(size_t)r * 256 + k] = f2bf(v);
        }
    } else {                            // Abuf cols [500,1088): x + pad
        const int row = b - 2432;
        for (int c = 500 + t; c < KP; c += 256) {
            const float v = (c < 500 + MDIM) ? x[(size_t)row * MDIM + (c - 500)] : 0.f;
            Abuf[(size_t)row * KP + c] = f2bf(v);
        }
    }
}

// generic bf16 MFMA GEMM: C[m][n] = sum_k A[m][k]*B[n][k] (+bias[n]); f32/bf16 out
__global__ __launch_bounds__(256) void k_gemm(
    const ushort_t* __restrict__ A, int lda,
    const ushort_t* __restrict__ B, int ldb,
    void* __restrict__ Cp, int ldc,
    const float* __restrict__ bias,
    int ksteps, int ntiles, int nlim, int bf16out)
{
    __shared__ __align__(16) ushort_t As[64 * 32];
    __shared__ __align__(16) ushort_t Bs[64 * 32];
    const int tid  = threadIdx.x;
    const int lane = tid & 63, wave = tid >> 6;
    const int wm = wave >> 1, wn = wave & 1;
    const int m0 = ((int)blockIdx.x / ntiles) * 64;
    const int n0 = ((int)blockIdx.x % ntiles) * 64;

    const int srow = tid >> 2;
    const int cs   = tid & 3;
    const int cl   = cs ^ ((srow >> 1) & 3);
    const ushort_t* gA = A + (size_t)(m0 + srow) * lda + cl * 8;
    const ushort_t* gB = B + (size_t)(n0 + srow) * ldb + cl * 8;
    ushort_t* lA = &As[tid * 8];
    ushort_t* lB = &Bs[tid * 8];

    const int q  = lane >> 4;
    const int fr = lane & 15;
    int aoff[2], boff[2];
#pragma unroll
    for (int s = 0; s < 2; ++s) {
        const int ra = wm * 32 + s * 16 + fr;
        aoff[s] = (ra * 4 + (q ^ ((ra >> 1) & 3))) * 8;
        const int rb = wn * 32 + s * 16 + fr;
        boff[s] = (rb * 4 + (q ^ ((rb >> 1) & 3))) * 8;
    }

    f32x4 acc[2][2] = {};
    for (int ks = 0; ks < ksteps; ++ks) {
        const int k0 = ks * 32;
        async_copy16(gA + k0, lA);
        async_copy16(gB + k0, lB);
        __syncthreads();
        short8 a[2], b[2];
#pragma unroll
        for (int s = 0; s < 2; ++s) {
            a[s] = *(const short8*)&As[aoff[s]];
            b[s] = *(const short8*)&Bs[boff[s]];
        }
#pragma unroll
        for (int ms = 0; ms < 2; ++ms)
#pragma unroll
            for (int ns = 0; ns < 2; ++ns)
                acc[ms][ns] = __builtin_amdgcn_mfma_f32_16x16x32_bf16(
                    a[ms], b[ns], acc[ms][ns], 0, 0, 0);
        __syncthreads();
    }

#pragma unroll
    for (int ms = 0; ms < 2; ++ms)
#pragma unroll
        for (int ns = 0; ns < 2; ++ns) {
            const int n_abs = n0 + wn * 32 + ns * 16 + fr;
            if (n_abs >= nlim) continue;
            const float bv = bias ? bias[n_abs] : 0.f;
#pragma unroll
            for (int reg = 0; reg < 4; ++reg) {
                const int m_abs = m0 + wm * 32 + ms * 16 + q * 4 + reg;
                const float v = acc[ms][ns][reg] + bv;
                if (bf16out) ((ushort_t*)Cp)[(size_t)m_abs * ldc + n_abs] = f2bf(v);
                else         ((float*)Cp)[(size_t)m_abs * ldc + n_abs] = v;
            }
        }
}

// LN(relu(Epre + enc_b)) -> Abuf cols [0,250). One wave per row, us4 loads.
__global__ __launch_bounds__(256) void k_lnenc(const ushort_t* __restrict__ Epre,
    const float* __restrict__ eb, const float* __restrict__ eg,
    const float* __restrict__ ebt, ushort_t* __restrict__ Abuf)
{
    const int wave = threadIdx.x >> 6, lane = threadIdx.x & 63;
    const int row = blockIdx.x * 4 + wave;
    const int c0 = 4 * lane;

    const us4 v = *(const us4*)&Epre[(size_t)row * 256 + c0];
    float y[4]; float sm = 0.f, sq = 0.f;
#pragma unroll
    for (int t = 0; t < 4; ++t) {
        const int cc = c0 + t;
        float z = 0.f;
        if (cc < H) z = fmaxf(bf2f(v[t]) + eb[cc], 0.f);
        y[t] = z; sm += z; sq += z * z;
    }
    wave_reduce2(sm, sq);
    const float mu = sm * (1.f / H);
    const float rs = __builtin_amdgcn_rsqf(sq * (1.f / H) - mu * mu + EPS);
    ushort_t o[4];
#pragma unroll
    for (int t = 0; t < 4; ++t) {
        const int cc = c0 + t;
        o[t] = (cc < H) ? f2bf((y[t] - mu) * rs * eg[cc] + ebt[cc]) : (ushort_t)0;
    }
    ushort_t* dst = Abuf + (size_t)row * KP + c0;
    if (c0 + 3 < H) { *(us4*)dst = (us4){o[0], o[1], o[2], o[3]}; }
    else {
        if (c0 + 1 < H) *(us2*)dst = (us2){o[0], o[1]};
    }
}

// Co[r][0:256] = LN(relu(P_g + Q_qr + core_b)) bf16. One wave per GROUP.
// All 7 partner Q rows prefetched; reductions interleaved across rows.
__global__ __launch_bounds__(256) void k_core(const ushort_t* __restrict__ PQb,
    const float* __restrict__ core_b, const float* __restrict__ core_g,
    const float* __restrict__ core_bt, ushort_t* __restrict__ Co)
{
    const int wave = threadIdx.x >> 6, lane = threadIdx.x & 63;
    const int g = blockIdx.x * 4 + wave;        // group 0..16383
    const int i = g & 7;
    const int c = lane * 4;

    const us4 pu = *(const us4*)&PQb[(size_t)g * PQS + c];
    us4 qu[7];
#pragma unroll
    for (int jj = 0; jj < 7; ++jj) {
        const int j = jj + (jj >= i ? 1 : 0);
        const int qr = (g & ~7) + j;
        qu[jj] = *(const us4*)&PQb[(size_t)qr * PQS + 256 + c];
    }
    float pe[4], cb[4], cg[4], cbt[4]; bool vl[4];
#pragma unroll
    for (int t = 0; t < 4; ++t) {
        vl[t]  = (c + t) < H;
        pe[t]  = bf2f(pu[t]);
        cb[t]  = vl[t] ? core_b[c + t]  : 0.f;
        cg[t]  = vl[t] ? core_g[c + t]  : 0.f;
        cbt[t] = vl[t] ? core_bt[c + t] : 0.f;
    }
    float z[7][4], red[7][2];
#pragma unroll
    for (int jj = 0; jj < 7; ++jj) {
        float sm = 0.f, sq = 0.f;
#pragma unroll
        for (int t = 0; t < 4; ++t) {
            const float zz = vl[t] ? fmaxf(pe[t] + bf2f(qu[jj][t]) + cb[t], 0.f) : 0.f;
            z[jj][t] = zz; sm += zz; sq = fmaf(zz, zz, sq);
        }
        red[jj][0] = sm; red[jj][1] = sq;
    }
    // interleaved reduction: 14 independent chains
#pragma unroll
    for (int m = 1; m < 64; m <<= 1)
#pragma unroll
        for (int jj = 0; jj < 7; ++jj) {
            red[jj][0] += __shfl_xor(red[jj][0], m, 64);
            red[jj][1] += __shfl_xor(red[jj][1], m, 64);
        }
#pragma unroll
    for (int jj = 0; jj < 7; ++jj) {
        const float mu = red[jj][0] * (1.f / H);
        const float rs = __builtin_amdgcn_rsqf(red[jj][1] * (1.f / H) - mu * mu + EPS);
        us4 o;
#pragma unroll
        for (int t = 0; t < 4; ++t)
            o[t] = vl[t] ? f2bf((z[jj][t] - mu) * rs * cg[t] + cbt[t]) : (ushort_t)0;
        *(us4*)&Co[((size_t)g * 7 + jj) * 256 + c] = o;
    }
}

// Cs[r][0:352] = Co_r @ [ctxW|attW1]^T (bf16 out). Pure async-staged GEMM:
// M=64/block, N=384 resident. 512 thr = 8 waves (2x4); acc[2][6] = 48 AGPR/wave.
__global__ __launch_bounds__(512, 4) void k_cs(
    const ushort_t* __restrict__ Co,
    const ushort_t* __restrict__ Wca,   // [384][256] bf16
    ushort_t* __restrict__ Cs)
{
    __shared__ __align__(16) ushort_t As[64 * 32];    // 4096 B
    __shared__ __align__(16) ushort_t Bs[384 * 32];   // 24576 B
    const int tid = threadIdx.x, lane = tid & 63, wave = tid >> 6;
    const int wm = wave >> 2, wn = wave & 3;
    const int R0 = (int)blockIdx.x * 64;

    const int ar = tid >> 2, acb = tid & 3;
    const bool aon = tid < 256;
    const int acl = acb ^ ((ar >> 1) & 3);
    const ushort_t* gA = Co + (size_t)(R0 + ar) * 256 + acl * 8;

    const int q = lane >> 4, fr = lane & 15;

    f32x4 acc[2][6] = {};
    for (int ks = 0; ks < 8; ++ks) {
        const int k0 = ks * 32;
        if (aon) async_copy16(gA + k0, &As[tid * 8]);
#pragma unroll
        for (int it = 0; it < 3; ++it) {
            const int ci  = it * 512 + tid;
            const int rb  = ci >> 2, cb2 = ci & 3;
            const int clb = cb2 ^ ((rb >> 1) & 3);
            async_copy16(Wca + (size_t)rb * 256 + k0 + clb * 8, &Bs[ci * 8]);
        }
        __syncthreads();
        short8 a[2];
#pragma unroll
        for (int ms = 0; ms < 2; ++ms) {
            const int row = wm * 32 + ms * 16 + fr;
            a[ms] = *(const short8*)&As[(row * 4 + (q ^ ((row >> 1) & 3))) * 8];
        }
#pragma unroll
        for (int nt = 0; nt < 6; ++nt) {
            const int n = wn * 96 + nt * 16 + fr;
            const short8 b = *(const short8*)&Bs[(n * 4 + (q ^ ((n >> 1) & 3))) * 8];
#pragma unroll
            for (int ms = 0; ms < 2; ++ms)
                acc[ms][nt] = __builtin_amdgcn_mfma_f32_16x16x32_bf16(
                    a[ms], b, acc[ms][nt], 0, 0, 0);
        }
        __syncthreads();
    }

#pragma unroll
    for (int ms = 0; ms < 2; ++ms)
#pragma unroll
        for (int nt = 0; nt < 6; ++nt) {
            const int col = wn * 96 + nt * 16 + fr;
            if (col >= CSLD) continue;
#pragma unroll
            for (int reg = 0; reg < 4; ++reg) {
                const int row = R0 + wm * 32 + ms * 16 + q * 4 + reg;
                Cs[(size_t)row * CSLD + col] = f2bf(acc[ms][nt][reg]);
            }
        }
}

// eff[g] = sum_j sigmoid(att(row)) * LN_ctx(row). One wave per group.
// All 7 rows prefetched; 35 reduction chains interleaved.
// NOTE: att columns 250..255 fall in the e<4 lane range (lane 62/63) — the
// e<4 path MUST dispatch on eC/eA per element (round-10 bug: ctx-only).
__global__ __launch_bounds__(256) void k_eff(const ushort_t* __restrict__ Cs,
    const float* __restrict__ ctx_b, const float* __restrict__ ctx_g, const float* __restrict__ ctx_bt,
    const float* __restrict__ att_b1, const float* __restrict__ att_g, const float* __restrict__ att_bt,
    const float* __restrict__ attW2, const float* __restrict__ att_b2,
    ushort_t* __restrict__ Abuf)
{
    const int wave = threadIdx.x >> 6, lane = threadIdx.x & 63;
    const int g = blockIdx.x * 4 + wave;
    const int c0 = 4 * lane;           // 0..252
    const int c1 = 256 + 2 * lane;     // 256..382, valid while lane<48
    const bool l48 = lane < 48;

    int ce[6]; bool eC[6], eA[6]; float b_[6], g_[6], bt_[6], w2_[6], gw[6];
#pragma unroll
    for (int e = 0; e < 6; ++e) {
        ce[e] = (e < 4) ? (c0 + e) : (c1 + (e - 4));
        const bool vld = (e < 4) || l48;
        eC[e] = vld && (ce[e] < H);
        eA[e] = vld && (ce[e] >= H) && (ce[e] < H + HA);
        if (eC[e])      { b_[e] = ctx_b[ce[e]]; g_[e] = ctx_g[ce[e]]; bt_[e] = ctx_bt[ce[e]]; w2_[e] = 0.f; }
        else if (eA[e]) { const int ca = ce[e] - H;
                          b_[e] = att_b1[ca]; g_[e] = att_g[ca]; bt_[e] = att_bt[ca]; w2_[e] = attW2[ca]; }
        else            { b_[e] = g_[e] = bt_[e] = w2_[e] = 0.f; }
        gw[e] = eA[e] ? g_[e] * w2_[e] : 0.f;
    }
    // row-invariant attention sums
    float sgw = 0.f, sbw = 0.f;
#pragma unroll
    for (int e = 0; e < 6; ++e) if (eA[e]) {
        sgw += g_[e] * w2_[e];
        sbw += bt_[e] * w2_[e];
    }
    wave_reduce2(sgw, sbw);
    const float ab2 = att_b2[0] + sbw;

    // Phase A: prefetch all 7 rows
    us4 v0[7]; us2 v1[7];
#pragma unroll
    for (int jj = 0; jj < 7; ++jj) {
        const size_t base = ((size_t)g * 7 + jj) * CSLD;
        v0[jj] = *(const us4*)&Cs[base + c0];
        v1[jj] = l48 ? *(const us2*)&Cs[base + c1] : (us2){0, 0};
    }

    // Phase B: elementwise partial sums per row (eC/eA dispatch on ALL 6 slots)
    float z[7][4], red[7][5];
#pragma unroll
    for (int jj = 0; jj < 7; ++jj) {
        float smc = 0.f, sqc = 0.f, sma = 0.f, sqa = 0.f, szgw = 0.f;
#pragma unroll
        for (int e = 0; e < 6; ++e) {
            const float raw = (e < 4) ? bf2f(v0[jj][e]) : bf2f(v1[jj][e - 4]);
            float zz = 0.f;
            if (eC[e]) {
                zz = fmaxf(raw + b_[e], 0.f);
                smc += zz; sqc = fmaf(zz, zz, sqc);
            } else if (eA[e]) {
                const float za = ftanh(raw + b_[e]);
                sma += za; sqa = fmaf(za, za, sqa);
                szgw = fmaf(za, gw[e], szgw);
            }
            if (e < 4) z[jj][e] = zz;
        }
        red[jj][0] = smc; red[jj][1] = sqc; red[jj][2] = sma;
        red[jj][3] = sqa; red[jj][4] = szgw;
    }

    // Phase C: 35 interleaved reduction chains
#pragma unroll
    for (int m = 1; m < 64; m <<= 1)
#pragma unroll
        for (int jj = 0; jj < 7; ++jj)
#pragma unroll
            for (int v = 0; v < 5; ++v)
                red[jj][v] += __shfl_xor(red[jj][v], m, 64);

    // Phase D: per-row scalars + accumulation
    float A4[4] = {0.f, 0.f, 0.f, 0.f};
    float S0 = 0.f, S1 = 0.f;
#pragma unroll
    for (int jj = 0; jj < 7; ++jj) {
        const float muC = red[jj][0] * (1.f / H);
        const float rsC = __builtin_amdgcn_rsqf(red[jj][1] * (1.f / H) - muC * muC + EPS);
        const float muA = red[jj][2] * (1.f / HA);
        const float rsA = __builtin_amdgcn_rsqf(red[jj][3] * (1.f / HA) - muA * muA + EPS);
        const float dot = rsA * (red[jj][4] - muA * sgw) + ab2;
        const float ag  = fsigmoid(dot);
        const float cj  = ag * rsC;
        S0 += ag; S1 = fmaf(cj, muC, S1);
#pragma unroll
        for (int e = 0; e < 4; ++e) A4[e] = fmaf(cj, z[jj][e], A4[e]);
    }
    ushort_t o[4];
#pragma unroll
    for (int e = 0; e < 4; ++e)
        o[e] = f2bf(g_[e] * (A4[e] - S1) + bt_[e] * S0);
    ushort_t* dst = Abuf + (size_t)g * KP + H + c0;
    if (c0 + 1 < H) *(us2*)dst       = (us2){o[0], o[1]};
    if (c0 + 3 < H) *(us2*)(dst + 2) = (us2){o[2], o[3]};
}

extern "C" void kernel_launch(void* const* d_in, const int* in_sizes, int n_in,
                              void* d_out, int out_size, void* d_ws, size_t ws_size,
                              hipStream_t stream)
{
    const float* x      = (const float*)d_in[0];
    const float* state  = (const float*)d_in[1];
    const float* enc_W  = (const float*)d_in[2];
    const float* enc_b  = (const float*)d_in[3];
    const float* enc_g  = (const float*)d_in[4];
    const float* enc_bt = (const float*)d_in[5];
    const float* core_W = (const float*)d_in[6];
    const float* core_b = (const float*)d_in[7];
    const float* core_g = (const float*)d_in[8];
    const float* core_bt= (const float*)d_in[9];
    const float* ctx_W  = (const float*)d_in[10];
    const float* ctx_b  = (const float*)d_in[11];
    const float* ctx_g  = (const float*)d_in[12];
    const float* ctx_bt = (const float*)d_in[13];
    const float* att_W1 = (const float*)d_in[14];
    const float* att_b1 = (const float*)d_in[15];
    const float* att_g  = (const float*)d_in[16];
    const float* att_bt = (const float*)d_in[17];
    const float* att_W2 = (const float*)d_in[18];
    const float* att_b2 = (const float*)d_in[19];
    const float* out_W  = (const float*)d_in[20];
    const float* out_b  = (const float*)d_in[21];
    float* out = (float*)d_out;

    // layout (ushort units); Sb/Epre/PQb alias the Cs region (dead before k_cs)
    ushort_t* Abuf = (ushort_t*)d_ws;                   // 16384*1088      (35.7 MB)
    ushort_t* Wt   = Abuf + (size_t)ROWS * KP;          // 256*1088
    ushort_t* Wpq  = Wt + (size_t)256 * KP;             // 512*256
    ushort_t* Wca  = Wpq + (size_t)512 * 256;           // 384*256
    ushort_t* Wenc = Wca + (size_t)384 * 256;           // 256*256
    ushort_t* Co   = Wenc + (size_t)256 * 256;          // 114688*256     (58.7 MB)
    ushort_t* Cs   = Co + (size_t)PROWS * 256;          // 114688*352     (80.7 MB)
    ushort_t* Sb   = Cs;                                // 16384*256  (aliased)
    ushort_t* Epre = Sb + (size_t)ROWS * 256;           // 16384*256  (aliased)
    ushort_t* PQb  = Epre + (size_t)ROWS * 256;         // 16384*512  (aliased)

    k_prep  <<<2432 + ROWS, 256, 0, stream>>>(out_W, core_W, ctx_W, att_W1, enc_W,
                                              state, x, Wt, Wpq, Wca, Wenc, Sb, Abuf);
    // Epre = state @ enc_W  (bf16 MFMA)
    k_gemm  <<<(ROWS / 64) * 4, 256, 0, stream>>>(Sb, 256, Wenc, 256, Epre, 256,
                                                  nullptr, 8, 4, 256, 1);
    k_lnenc <<<ROWS / 4, 256, 0, stream>>>(Epre, enc_b, enc_g, enc_bt, Abuf);
    // PQb = s1 @ [W_top | W_bot]  (bf16 MFMA, bf16 out)
    k_gemm  <<<(ROWS / 64) * 8, 256, 0, stream>>>(Abuf, KP, Wpq, 256, PQb, PQS,
                                                  nullptr, 8, 8, 512, 1);
    k_core  <<<ROWS / 4, 256, 0, stream>>>(PQb, core_b, core_g, core_bt, Co);
    k_cs    <<<PROWS / 64, 512, 0, stream>>>(Co, Wca, Cs);
    k_eff   <<<ROWS / 4, 256, 0, stream>>>(Cs, ctx_b, ctx_g, ctx_bt,
                                           att_b1, att_g, att_bt, att_W2, att_b2,
                                           Abuf);
    // out = [s1 | eff | x] @ out_W + b  (bf16 MFMA, fp32 out)
    k_gemm  <<<(ROWS / 64) * 4, 256, 0, stream>>>(Abuf, KP, Wt, KP, out, H,
                                                  out_b, KP / 32, 4, H, 0);
}